// Round 3
// baseline (298.438 us; speedup 1.0000x reference)
//
#include <hip/hip_runtime.h>

// TreeAttentionV2: B=8, T=1024, C=1024 (L=4,R=256), H=16, hd=64.
// Pipeline (all fp16 MFMA, fp32 accumulate):
//   1. conv_x:    x fp32 (8192x1024) -> xh fp16
//   2. tconv x2:  w_attn -> waT fp16 (3072x1024), w_proj -> wpT fp16 (1024x1024)
//   3. gemm8p<split3>: qn/kn/vn = xh @ waT^T + b_attn (8-phase pipelined)
//   4. pack_k:    kn -> kP, MFMA-A-fragment order
//   5. pack_v:    vn -> vP, MFMA-B-fragment order
//   6. attn v8:   32-row q-tile (r1 amortization), 1024 threads = 16 waves k-sliced
//                 (64 k each) -> E 64KB but 2 blocks/CU = 8 waves/SIMD (needs <=64 VGPR).
//                 XCD-swizzled grid: each bh's 32 q-tiles on one XCD (K/V L2 locality).
//   7. gemm8p<f32>: out = y @ wpT^T + b_proj
//
// Workspace (88 MiB, unchanged):
//   [0,16M)   xh -> vP ; [16M,32M) qn ; [32M,48M) kn -> y ; [48M,64M) vn
//   [64M,80M) kP ; [80M,86M) waT ; [86M,88M) wpT

typedef _Float16 half8 __attribute__((ext_vector_type(8)));
typedef _Float16 half4_t __attribute__((ext_vector_type(4)));
typedef _Float16 half2_t __attribute__((ext_vector_type(2)));
typedef float floatx4 __attribute__((ext_vector_type(4)));
typedef float floatx2 __attribute__((ext_vector_type(2)));

__device__ __forceinline__ void gl2lds16(const void* gsrc, void* lds) {
    __builtin_amdgcn_global_load_lds(
        (const __attribute__((address_space(1))) unsigned int*)gsrc,
        (__attribute__((address_space(3))) unsigned int*)lds,
        16, 0, 0);
}

// ---------------- elementwise convert fp32 -> fp16 ----------------
__global__ __launch_bounds__(256) void conv_x(const float4* __restrict__ in,
                                              _Float16* __restrict__ out, int n4) {
    int idx = blockIdx.x * blockDim.x + threadIdx.x;
    int stride = gridDim.x * blockDim.x;
    for (int i = idx; i < n4; i += stride) {
        float4 v = in[i];
        half4_t h = { (_Float16)v.x, (_Float16)v.y, (_Float16)v.z, (_Float16)v.w };
        *(half4_t*)(out + (size_t)i * 4) = h;
    }
}

// ------------- transpose + convert: out[n][k] = in[k][n] ----------
__global__ __launch_bounds__(256) void tconv(const float* __restrict__ in,
                                             _Float16* __restrict__ out, int R, int C) {
    __shared__ _Float16 t[64 * 65];
    int bx = blockIdx.x, by = blockIdx.y;
#pragma unroll
    for (int it = 0; it < 16; ++it) {
        int idx = it * 256 + threadIdx.x;
        int r = idx >> 6, c = idx & 63;
        t[c * 65 + r] = (_Float16)in[(size_t)(by * 64 + r) * C + bx * 64 + c];
    }
    __syncthreads();
#pragma unroll
    for (int it = 0; it < 16; ++it) {
        int idx = it * 256 + threadIdx.x;
        int rn = idx >> 6, ck = idx & 63;
        out[(size_t)(bx * 64 + rn) * R + by * 64 + ck] = t[rn * 65 + ck];
    }
}

// ------------- pack K into A-fragment order -------------
__global__ __launch_bounds__(256) void pack_k(const _Float16* __restrict__ kn,
                                              _Float16* __restrict__ kP) {
    int cid = blockIdx.x * 256 + threadIdx.x;
    int lane = cid & 63, half = (cid >> 6) & 1, kb = (cid >> 7) & 63, bh = cid >> 13;
    int l15 = lane & 15, quad = lane >> 4;
    int b = bh >> 4, h = bh & 15;
    int t = kb * 16 + l15, d = half * 32 + quad * 8;
    half8 v = *(const half8*)(kn + (size_t)(b * 1024 + t) * 1024 + h * 64 + d);
    *(half8*)(kP + (size_t)cid * 8) = v;
}

// ------------- pack V (transposed) into B-fragment order -------------
__global__ __launch_bounds__(256) void pack_v(const _Float16* __restrict__ vn,
                                              _Float16* __restrict__ vP) {
    __shared__ _Float16 s[32][72];
    int kbv = blockIdx.x, bh = blockIdx.y;
    int b = bh >> 4, h = bh & 15;
    int tid = threadIdx.x;
    {
        int row = tid >> 3, piece = tid & 7;
        *(half8*)&s[row][piece * 8] =
            *(const half8*)(vn + (size_t)(b * 1024 + kbv * 32 + row) * 1024 + h * 64 + piece * 8);
    }
    __syncthreads();
    {
        int l15v = tid & 15, quad = (tid >> 4) & 3, cf = tid >> 6;
        half8 o;
#pragma unroll
        for (int j = 0; j < 8; ++j) o[j] = s[quad * 8 + j][cf * 16 + l15v];
        *(half8*)(vP + ((size_t)(bh * 32 + kbv) * 256 + tid) * 8) = o;
    }
}

// ================= 8-phase pipelined GEMM: C(MxN) = A(MxK) * BT(NxK)^T + bias =================
// BM=256, BN=128, BK=64, K=1024 fixed. 512 threads = 8 waves (4M x 2N), per-wave 64x64.
// LDS 96 KiB, XOR-swizzled (T2) via inverse-swizzled global source (rule #21).
// Counted vmcnt (T4), never 0 in loop; raw s_barrier; setprio around MFMA (T5).

#define GBAR __builtin_amdgcn_s_barrier()
#define WLGKM do { asm volatile("s_waitcnt lgkmcnt(0)" ::: "memory"); } while (0)
#define WVM2  do { asm volatile("s_waitcnt vmcnt(2)"   ::: "memory"); } while (0)

#define LDA(buf, rg)                                                                          \
    do {                                                                                      \
        _Pragma("unroll") for (int i = 0; i < 2; ++i) {                                       \
            int r_ = wm * 64 + ((rg) * 2 + i) * 16 + l15;                                     \
            _Pragma("unroll") for (int kk = 0; kk < 2; ++kk)                                  \
                a[i][kk] = *(const half8*)(sA + (buf) * 32768 + r_ * 128 +                    \
                                           ((((kk << 2) + quad) ^ (r_ & 7)) << 4));           \
        }                                                                                     \
    } while (0)

#define LDB(buf, cg, bb)                                                                      \
    do {                                                                                      \
        _Pragma("unroll") for (int j = 0; j < 2; ++j) {                                       \
            int r_ = wn * 64 + ((cg) * 2 + j) * 16 + l15;                                     \
            _Pragma("unroll") for (int kk = 0; kk < 2; ++kk)                                  \
                bb[j][kk] = *(const half8*)(sB + (buf) * 16384 + r_ * 128 +                   \
                                            ((((kk << 2) + quad) ^ (r_ & 7)) << 4));          \
        }                                                                                     \
    } while (0)

#define MMA(rg, cg, bb)                                                                       \
    do {                                                                                      \
        __builtin_amdgcn_s_setprio(1);                                                        \
        _Pragma("unroll") for (int kk = 0; kk < 2; ++kk)                                      \
            _Pragma("unroll") for (int i = 0; i < 2; ++i)                                     \
                _Pragma("unroll") for (int j = 0; j < 2; ++j)                                  \
                    acc[(rg) * 2 + i][(cg) * 2 + j] = __builtin_amdgcn_mfma_f32_16x16x32_f16( \
                        a[i][kk], bb[j][kk], acc[(rg) * 2 + i][(cg) * 2 + j], 0, 0, 0);       \
        __builtin_amdgcn_s_setprio(0);                                                        \
    } while (0)

template <bool SPLIT3>
__global__ __launch_bounds__(512, 2) void gemm8p(const _Float16* __restrict__ A,
                                                 const _Float16* __restrict__ BT,
                                                 const float* __restrict__ bias,
                                                 void* __restrict__ o0, void* __restrict__ o1,
                                                 void* __restrict__ o2, int N) {
    __shared__ __attribute__((aligned(16))) char lds[98304];
    char* sA = lds;           // + buf*32768  (+ half*16384 on stage side)
    char* sB = lds + 65536;   // + buf*16384  (+ half*8192  on stage side)
    int tid = threadIdx.x;
    int W = tid >> 6, lane = tid & 63, quad = lane >> 4, l15 = lane & 15;
    int wm = W >> 1, wn = W & 1;
    int m0 = blockIdx.y * 256, n0 = blockIdx.x * 128;

    auto stA = [&](int buf, int half, int k0) {
#pragma unroll
        for (int rnd = 0; rnd < 2; ++rnd) {
            int c = rnd * 512 + tid;
            int row = c >> 3;
            int q = (c & 7) ^ (row & 7);
            const _Float16* src = A + (size_t)(m0 + half * 128 + row) * 1024 + k0 + q * 8;
            int off = __builtin_amdgcn_readfirstlane(buf * 32768 + half * 16384 +
                                                     rnd * 8192 + (W << 10));
            gl2lds16(src, sA + off);
        }
    };
    auto stB = [&](int buf, int half, int k0) {
        int row = tid >> 3;
        int q = (tid & 7) ^ (row & 7);
        const _Float16* src = BT + (size_t)(n0 + half * 64 + row) * 1024 + k0 + q * 8;
        int off = __builtin_amdgcn_readfirstlane(buf * 16384 + half * 8192 + (W << 10));
        gl2lds16(src, sB + off);
    };

    half8 a[2][2], b0[2][2], b1[2][2];
    floatx4 acc[4][4] = {};

    stA(0, 0, 0); stA(0, 1, 0);
    stB(0, 0, 0); stB(0, 1, 0);
    stB(1, 0, 64); stB(1, 1, 64);
    WVM2;
    GBAR;

#pragma unroll 1
    for (int t = 0; t < 16; t += 2) {
        int k1 = (t + 1) << 6;
        int k2 = ((t + 2) & 15) << 6;
        int k3 = ((t + 3) & 15) << 6;
        // P1
        LDA(0, 0); LDB(0, 0, b0); stA(1, 0, k1);
        GBAR; WLGKM; MMA(0, 0, b0); GBAR;
        // P2
        LDB(0, 1, b1); stA(1, 1, k1);
        GBAR; WLGKM; MMA(0, 1, b1); GBAR;
        // P3
        LDA(0, 1); stB(0, 0, k2);
        GBAR; WLGKM; MMA(1, 1, b1); GBAR;
        // P4
        stB(0, 1, k2); WVM2;
        GBAR; WLGKM; MMA(1, 0, b0); GBAR;
        // P5
        LDA(1, 0); LDB(1, 0, b0); stA(0, 0, k2);
        GBAR; WLGKM; MMA(0, 0, b0); GBAR;
        // P6
        LDB(1, 1, b1); stA(0, 1, k2);
        GBAR; WLGKM; MMA(0, 1, b1); GBAR;
        // P7
        LDA(1, 1); stB(1, 0, k3);
        GBAR; WLGKM; MMA(1, 1, b1); GBAR;
        // P8
        stB(1, 1, k3); WVM2;
        GBAR; WLGKM; MMA(1, 0, b0); GBAR;
    }

    _Float16* hbase = nullptr;
    if (SPLIT3) {
        int sec = n0 >> 10;
        hbase = (_Float16*)(sec == 0 ? o0 : (sec == 1 ? o1 : o2));
    }
#pragma unroll
    for (int cf = 0; cf < 4; ++cf) {
        int gn = n0 + wn * 64 + cf * 16 + l15;
        float bv = bias[gn];
        int cn = gn & 1023;
#pragma unroll
        for (int rf = 0; rf < 4; ++rf) {
            int gmBase = m0 + wm * 64 + rf * 16 + quad * 4;
#pragma unroll
            for (int r = 0; r < 4; ++r) {
                float v = acc[rf][cf][r] + bv;
                if (SPLIT3) hbase[(size_t)(gmBase + r) * 1024 + cn] = (_Float16)v;
                else        ((float*)o0)[(size_t)(gmBase + r) * N + gn] = v;
            }
        }
    }
}

// ------------------------------- attention v8 -------------------------------
// grid 4096 blocks (32 q-tiles x 128 bh), XCD-swizzled; 1024 threads = 16 waves.
// Wave w owns k-slice [w*64, w*64+64). 32-row q-tile restores r1's K-load
// amortization (nf=2 MFMAs per K-frag pair; per-block K/V L2 read amortized
// over 32 q-rows); 16-wave blocks give 2 blocks/CU = 8 waves/SIMD despite 64KB E.
// LDS: E = 32 q x 1024 k fp16 (64KB, xor-swizzled 16B granules); lsum 16x32 f32.
// Phase1: S^T = K.Q^T, e = exp2(s*c) -> E + reg rowsum (E traffic is wave-private).
// Phase2: PV over wave's k-slice; normalize+threshold fused into A-frags.
// Phase3: two-stage reduce of 16 k-slice partials (waves 8-15 write, 0-7 RMW,
//         then all threads sum 8 slices; red reuses E, 8x32x64 f32 = 64KB exact).
__device__ __forceinline__ int esw(int row, int colByte) {
    return row * 2048 + (colByte ^ ((row & 7) << 4));
}

__global__ __launch_bounds__(1024, 8) void attn(const _Float16* __restrict__ qn,
                                                const _Float16* __restrict__ kP,
                                                const _Float16* __restrict__ vP,
                                                _Float16* __restrict__ y) {
    __shared__ __attribute__((aligned(16))) _Float16 E[32 * 1024];
    __shared__ float lsum[16][32];
    char* Eb = (char*)E;
    int tid = threadIdx.x;
    int W = tid >> 6, lane = tid & 63, quad = lane >> 4, l15 = lane & 15;
    // XCD swizzle: flat = by*32+bx round-robins XCDs (flat&7); give each XCD a
    // contiguous 512-block chunk so one bh's 32 q-tiles share one L2. Bijective
    // (4096 % 8 == 0).
    int flat = blockIdx.y * 32 + blockIdx.x;
    int swz = (flat & 7) * 512 + (flat >> 3);
    int qt = swz & 31, bh = swz >> 5;
    int b = bh >> 4, h = bh & 15;
    int q0 = qt * 32;

    // --- Q as B-fragments (B[k=quad*8+j][n=l15]): n = q-row, k = d ---
    half8 bq[2][2];
#pragma unroll
    for (int nf = 0; nf < 2; ++nf)
#pragma unroll
        for (int ks = 0; ks < 2; ++ks)
            bq[nf][ks] = *(const half8*)(qn + (size_t)(b * 1024 + q0 + nf * 16 + l15) * 1024 +
                                         h * 64 + ks * 32 + quad * 8);

    // --- Phase 1: S^T = K.Q^T, e = exp2(s*c) -> E; rowsum partials in regs ---
    float lpart[2] = {0.f, 0.f};
#pragma unroll
    for (int mt = 0; mt < 4; ++mt) {
        int kb = W * 4 + mt;
        const _Float16* kp = kP + ((size_t)(bh * 64 + kb) * 128 + lane) * 8;
        half8 ak0 = *(const half8*)(kp);            // contiguous 1KB per wave
        half8 ak1 = *(const half8*)(kp + 512);
#pragma unroll
        for (int nf = 0; nf < 2; ++nf) {
            floatx4 s = {};
            s = __builtin_amdgcn_mfma_f32_16x16x32_f16(ak0, bq[nf][0], s, 0, 0, 0);
            s = __builtin_amdgcn_mfma_f32_16x16x32_f16(ak1, bq[nf][1], s, 0, 0, 0);
            half4_t h4;
#pragma unroll
            for (int r = 0; r < 4; ++r) {
                // exp(min(s/8,10)) == exp2(min(s*0.125*log2e, 14.4269504))
                float e = __builtin_amdgcn_exp2f(fminf(s[r] * 0.18033688f, 14.4269504f));
                lpart[nf] += e;
                h4[r] = (_Float16)e;
            }
            int q = nf * 16 + l15;
            int kbyte = (W * 64 + mt * 16 + quad * 4) * 2;
            *(half4_t*)(Eb + q * 2048 + (kbyte ^ ((q & 7) << 4))) = h4;
        }
    }
    // reduce over the 4 quads (lanes sharing l15)
#pragma unroll
    for (int nf = 0; nf < 2; ++nf) {
        lpart[nf] += __shfl_xor(lpart[nf], 16);
        lpart[nf] += __shfl_xor(lpart[nf], 32);
    }
    if (lane < 16) {
        lsum[W][l15] = lpart[0];
        lsum[W][16 + l15] = lpart[1];
    }
    __syncthreads();

    // --- Phase 2: PV over wave's k-slice; normalize+threshold fused in regs ---
    half8 inv8[2], t8, z8;
#pragma unroll
    for (int j = 0; j < 8; ++j) { t8[j] = (_Float16)(-0.001f); z8[j] = (_Float16)0.f; }
#pragma unroll
    for (int rf = 0; rf < 2; ++rf) {
        float l = 0.f;
#pragma unroll
        for (int w = 0; w < 16; ++w) l += lsum[w][rf * 16 + l15];
        _Float16 invh = (_Float16)(1.0f / l);
#pragma unroll
        for (int j = 0; j < 8; ++j) inv8[rf][j] = invh;
    }

    floatx4 acc[2][4] = {};
#pragma unroll
    for (int kt = 0; kt < 2; ++kt) {
        int kk = W * 64 + kt * 32;
        half8 ap[2];
#pragma unroll
        for (int rf = 0; rf < 2; ++rf) {
            ap[rf] = *(const half8*)(Eb + esw(rf * 16 + l15, (kk + quad * 8) * 2));
            ap[rf] = ap[rf] * inv8[rf] + t8;                        // v_pk_fma_f16
            ap[rf] = __builtin_elementwise_max(ap[rf], z8);         // v_pk_max_f16
        }
        const _Float16* vbase = vP + ((size_t)(bh * 32 + (W * 2 + kt)) * 256 + lane) * 8;
        half8 bv[4];
#pragma unroll
        for (int cf = 0; cf < 4; ++cf)
            bv[cf] = *(const half8*)(vbase + cf * 512);             // contiguous 1KB / wave
#pragma unroll
        for (int rf = 0; rf < 2; ++rf)
#pragma unroll
            for (int cf = 0; cf < 4; ++cf)
                acc[rf][cf] = __builtin_amdgcn_mfma_f32_16x16x32_f16(ap[rf], bv[cf], acc[rf][cf], 0, 0, 0);
    }
    __syncthreads();   // all waves done reading E before reuse

    // --- Phase 3: two-stage reduce of 16 partials (red reuses E: 8x32x64 f32) ---
    float* red = (float*)E;
    if (W >= 8) {
#pragma unroll
        for (int rf = 0; rf < 2; ++rf)
#pragma unroll
            for (int cf = 0; cf < 4; ++cf)
#pragma unroll
                for (int r = 0; r < 4; ++r)
                    red[(W - 8) * 2048 + (rf * 16 + quad * 4 + r) * 64 + cf * 16 + l15] =
                        acc[rf][cf][r];
    }
    __syncthreads();
    if (W < 8) {
#pragma unroll
        for (int rf = 0; rf < 2; ++rf)
#pragma unroll
            for (int cf = 0; cf < 4; ++cf)
#pragma unroll
                for (int r = 0; r < 4; ++r) {
                    int idx = W * 2048 + (rf * 16 + quad * 4 + r) * 64 + cf * 16 + l15;
                    red[idx] += acc[rf][cf][r];
                }
    }
    __syncthreads();
    {
        int e2 = tid * 2;                 // 1024 thr x 2 = 2048 = 32x64
        int r = e2 >> 6, c = e2 & 63;
        floatx2 s = {};
#pragma unroll
        for (int w = 0; w < 8; ++w) s += *(const floatx2*)(red + w * 2048 + e2);
        half2_t hv = { (_Float16)s[0], (_Float16)s[1] };
        *(half2_t*)(y + (size_t)(b * 1024 + q0 + r) * 1024 + h * 64 + c) = hv;
    }
}

// ------------------------------- launcher -------------------------------
extern "C" void kernel_launch(void* const* d_in, const int* in_sizes, int n_in,
                              void* d_out, int out_size, void* d_ws, size_t ws_size,
                              hipStream_t stream) {
    const float* x  = (const float*)d_in[0];
    const float* wa = (const float*)d_in[1];
    const float* ba = (const float*)d_in[2];
    const float* wp = (const float*)d_in[3];
    const float* bp = (const float*)d_in[4];
    float* out = (float*)d_out;

    char* ws = (char*)d_ws;
    _Float16* xh  = (_Float16*)(ws);                    // [0,16M)  dead after gemm1
    _Float16* vP  = (_Float16*)(ws);                    //   -> vP (pack_v onward)
    _Float16* qn  = (_Float16*)(ws + 16777216);         // [16M,32M) live through attn
    _Float16* kn  = (_Float16*)(ws + 33554432);         // [32M,48M) dead after pack_k
    _Float16* y   = (_Float16*)(ws + 33554432);         //   -> y (attn onward)
    _Float16* vn  = (_Float16*)(ws + 50331648);         // [48M,64M) dead after pack_v
    _Float16* kP  = (_Float16*)(ws + 67108864);         // [64M,80M)
    _Float16* waT = (_Float16*)(ws + 83886080);         // [80M,86M)
    _Float16* wpT = (_Float16*)(ws + 90177536);         // [86M,88M)

    conv_x<<<4096, 256, 0, stream>>>((const float4*)x, xh, 8388608 / 4);
    tconv<<<dim3(48, 16), 256, 0, stream>>>(wa, waT, 1024, 3072);
    tconv<<<dim3(16, 16), 256, 0, stream>>>(wp, wpT, 1024, 1024);
    gemm8p<true><<<dim3(24, 32), 512, 0, stream>>>(xh, waT, ba, (void*)qn, (void*)kn, (void*)vn, 3072);
    pack_k<<<4096, 256, 0, stream>>>(kn, kP);
    pack_v<<<dim3(32, 128), 256, 0, stream>>>(vn, vP);
    attn<<<dim3(32, 128), 1024, 0, stream>>>(qn, kP, vP, y);
    gemm8p<false><<<dim3(8, 32), 512, 0, stream>>>(y, wpT, bp, (void*)out, nullptr, nullptr, 1024);
}

// Round 4
// 260.216 us; speedup vs baseline: 1.1469x; 1.1469x over previous
//
#include <hip/hip_runtime.h>

// TreeAttentionV2: B=8, T=1024, C=1024 (L=4,R=256), H=16, hd=64.
// Pipeline (all fp16 MFMA, fp32 accumulate):
//   1. conv_x:    x fp32 (8192x1024) -> xh fp16
//   2. tconv x2:  w_attn -> waT fp16 (3072x1024), w_proj -> wpT fp16 (1024x1024)
//   3. gemm8p<split3>: qn/kP/vP = xh @ waT^T + b_attn. 8-phase pipelined loop;
//                 epilogue stages C-tile in LDS (dead sA/sB) and writes Q rows,
//                 K in A-fragment order (kP), V^T in B-fragment order (vP) as
//                 16B coalesced chunks. pack_k / pack_v kernels are GONE.
//   4. attn v6+s: 32-row q-tile, 8 waves, k-sliced (proven r1 structure) +
//                 XCD-swizzled grid (r3-proven: FETCH 139->25MB).
//   5. gemm8p<f32>: out = y @ wpT^T + b_proj
//
// Workspace (88 MiB):
//   [0,16M)   y    (attn output; region free until attn)
//   [16M,32M) qn ; [32M,48M) kP ; [48M,64M) vP
//   [64M,70M) waT ; [70M,72M) wpT ; [72M,88M) xh (dead after gemm1)

typedef _Float16 half8 __attribute__((ext_vector_type(8)));
typedef _Float16 half4_t __attribute__((ext_vector_type(4)));
typedef float floatx4 __attribute__((ext_vector_type(4)));

__device__ __forceinline__ void gl2lds16(const void* gsrc, void* lds) {
    __builtin_amdgcn_global_load_lds(
        (const __attribute__((address_space(1))) unsigned int*)gsrc,
        (__attribute__((address_space(3))) unsigned int*)lds,
        16, 0, 0);
}

// ---------------- elementwise convert fp32 -> fp16 ----------------
__global__ __launch_bounds__(256) void conv_x(const float4* __restrict__ in,
                                              _Float16* __restrict__ out, int n4) {
    int idx = blockIdx.x * blockDim.x + threadIdx.x;
    int stride = gridDim.x * blockDim.x;
    for (int i = idx; i < n4; i += stride) {
        float4 v = in[i];
        half4_t h = { (_Float16)v.x, (_Float16)v.y, (_Float16)v.z, (_Float16)v.w };
        *(half4_t*)(out + (size_t)i * 4) = h;
    }
}

// ------------- transpose + convert: out[n][k] = in[k][n] ----------
__global__ __launch_bounds__(256) void tconv(const float* __restrict__ in,
                                             _Float16* __restrict__ out, int R, int C) {
    __shared__ _Float16 t[64 * 65];
    int bx = blockIdx.x, by = blockIdx.y;
#pragma unroll
    for (int it = 0; it < 16; ++it) {
        int idx = it * 256 + threadIdx.x;
        int r = idx >> 6, c = idx & 63;
        t[c * 65 + r] = (_Float16)in[(size_t)(by * 64 + r) * C + bx * 64 + c];
    }
    __syncthreads();
#pragma unroll
    for (int it = 0; it < 16; ++it) {
        int idx = it * 256 + threadIdx.x;
        int rn = idx >> 6, ck = idx & 63;
        out[(size_t)(bx * 64 + rn) * R + by * 64 + ck] = t[rn * 65 + ck];
    }
}

// ================= 8-phase pipelined GEMM =================
// BM=256, BN=128, BK=64, K=1024 fixed. 512 threads = 8 waves (4M x 2N), per-wave 64x64.
// LDS 96 KiB loop phase; epilogue reuses it as C-stage.
// kP chunk c holds K[t=(c>>7&63)*16+(c&15)][d=(c>>6&1)*32+((c>>4)&3)*8+j]  (c per bh<<13)
// vP chunk c holds V^T[d=((c&255)>>6)*16+(c&15)][k=(c>>8&31)*32+((c>>4)&3)*8+j] (c per bh<<13)

#define GBAR __builtin_amdgcn_s_barrier()
#define WLGKM do { asm volatile("s_waitcnt lgkmcnt(0)" ::: "memory"); } while (0)
#define WVM2  do { asm volatile("s_waitcnt vmcnt(2)"   ::: "memory"); } while (0)
#define WVM0  do { asm volatile("s_waitcnt vmcnt(0)"   ::: "memory"); } while (0)

#define LDA(buf, rg)                                                                          \
    do {                                                                                      \
        _Pragma("unroll") for (int i = 0; i < 2; ++i) {                                       \
            int r_ = wm * 64 + ((rg) * 2 + i) * 16 + l15;                                     \
            _Pragma("unroll") for (int kk = 0; kk < 2; ++kk)                                  \
                a[i][kk] = *(const half8*)(sA + (buf) * 32768 + r_ * 128 +                    \
                                           ((((kk << 2) + quad) ^ (r_ & 7)) << 4));           \
        }                                                                                     \
    } while (0)

#define LDB(buf, cg, bb)                                                                      \
    do {                                                                                      \
        _Pragma("unroll") for (int j = 0; j < 2; ++j) {                                       \
            int r_ = wn * 64 + ((cg) * 2 + j) * 16 + l15;                                     \
            _Pragma("unroll") for (int kk = 0; kk < 2; ++kk)                                  \
                bb[j][kk] = *(const half8*)(sB + (buf) * 16384 + r_ * 128 +                   \
                                            ((((kk << 2) + quad) ^ (r_ & 7)) << 4));          \
        }                                                                                     \
    } while (0)

#define MMA(rg, cg, bb)                                                                       \
    do {                                                                                      \
        __builtin_amdgcn_s_setprio(1);                                                        \
        _Pragma("unroll") for (int kk = 0; kk < 2; ++kk)                                      \
            _Pragma("unroll") for (int i = 0; i < 2; ++i)                                     \
                _Pragma("unroll") for (int j = 0; j < 2; ++j)                                  \
                    acc[(rg) * 2 + i][(cg) * 2 + j] = __builtin_amdgcn_mfma_f32_16x16x32_f16( \
                        a[i][kk], bb[j][kk], acc[(rg) * 2 + i][(cg) * 2 + j], 0, 0, 0);       \
        __builtin_amdgcn_s_setprio(0);                                                        \
    } while (0)

template <bool SPLIT3>
__global__ __launch_bounds__(512, 2) void gemm8p(const _Float16* __restrict__ A,
                                                 const _Float16* __restrict__ BT,
                                                 const float* __restrict__ bias,
                                                 void* __restrict__ o0, void* __restrict__ o1,
                                                 void* __restrict__ o2, int N) {
    __shared__ __attribute__((aligned(16))) char lds[98304];
    char* sA = lds;           // + buf*32768  (+ half*16384 on stage side)
    char* sB = lds + 65536;   // + buf*16384  (+ half*8192  on stage side)
    int tid = threadIdx.x;
    int W = tid >> 6, lane = tid & 63, quad = lane >> 4, l15 = lane & 15;
    int wm = W >> 1, wn = W & 1;
    int m0 = blockIdx.y * 256, n0 = blockIdx.x * 128;

    auto stA = [&](int buf, int half, int k0) {
#pragma unroll
        for (int rnd = 0; rnd < 2; ++rnd) {
            int c = rnd * 512 + tid;
            int row = c >> 3;
            int q = (c & 7) ^ (row & 7);
            const _Float16* src = A + (size_t)(m0 + half * 128 + row) * 1024 + k0 + q * 8;
            int off = __builtin_amdgcn_readfirstlane(buf * 32768 + half * 16384 +
                                                     rnd * 8192 + (W << 10));
            gl2lds16(src, sA + off);
        }
    };
    auto stB = [&](int buf, int half, int k0) {
        int row = tid >> 3;
        int q = (tid & 7) ^ (row & 7);
        const _Float16* src = BT + (size_t)(n0 + half * 64 + row) * 1024 + k0 + q * 8;
        int off = __builtin_amdgcn_readfirstlane(buf * 16384 + half * 8192 + (W << 10));
        gl2lds16(src, sB + off);
    };

    half8 a[2][2], b0[2][2], b1[2][2];
    floatx4 acc[4][4] = {};

    stA(0, 0, 0); stA(0, 1, 0);
    stB(0, 0, 0); stB(0, 1, 0);
    stB(1, 0, 64); stB(1, 1, 64);
    WVM2;
    GBAR;

#pragma unroll 1
    for (int t = 0; t < 16; t += 2) {
        int k1 = (t + 1) << 6;
        int k2 = ((t + 2) & 15) << 6;
        int k3 = ((t + 3) & 15) << 6;
        // P1
        LDA(0, 0); LDB(0, 0, b0); stA(1, 0, k1);
        GBAR; WLGKM; MMA(0, 0, b0); GBAR;
        // P2
        LDB(0, 1, b1); stA(1, 1, k1);
        GBAR; WLGKM; MMA(0, 1, b1); GBAR;
        // P3
        LDA(0, 1); stB(0, 0, k2);
        GBAR; WLGKM; MMA(1, 1, b1); GBAR;
        // P4
        stB(0, 1, k2); WVM2;
        GBAR; WLGKM; MMA(1, 0, b0); GBAR;
        // P5
        LDA(1, 0); LDB(1, 0, b0); stA(0, 0, k2);
        GBAR; WLGKM; MMA(0, 0, b0); GBAR;
        // P6
        LDB(1, 1, b1); stA(0, 1, k2);
        GBAR; WLGKM; MMA(0, 1, b1); GBAR;
        // P7
        LDA(1, 1); stB(1, 0, k3);
        GBAR; WLGKM; MMA(1, 1, b1); GBAR;
        // P8
        stB(1, 1, k3); WVM2;
        GBAR; WLGKM; MMA(1, 0, b0); GBAR;
    }

    if constexpr (!SPLIT3) {
        // proj epilogue: direct f32 writes (unchanged, proven)
#pragma unroll
        for (int cf = 0; cf < 4; ++cf) {
            int gn = n0 + wn * 64 + cf * 16 + l15;
            float bv = bias[gn];
#pragma unroll
            for (int rf = 0; rf < 4; ++rf) {
                int gmBase = m0 + wm * 64 + rf * 16 + quad * 4;
#pragma unroll
                for (int r = 0; r < 4; ++r)
                    ((float*)o0)[(size_t)(gmBase + r) * N + gn] = acc[rf][cf][r] + bv;
            }
        }
    } else {
        // ---- fused-pack epilogue: stage C-tile in LDS, write packed 16B chunks ----
        WVM0;          // trailing prefetch DMA must land before LDS reuse
        GBAR;
        int sec = n0 >> 10;          // 0=Q 1=K 2=V (BN=128 tiles never straddle)
        int nb = n0 & 1023;          // col base within section
        int b = m0 >> 10;            // batch (BM=256 stays within one b)
        int tb = m0 & 1023;          // token base
        _Float16* qno = (_Float16*)o0;
        _Float16* kPo = (_Float16*)o1;
        _Float16* vPo = (_Float16*)o2;
        if (sec == 2) {
            // V: stage transposed [n=128][m=256], row stride 528B (132 words % 32 = 4)
#pragma unroll
            for (int cf = 0; cf < 4; ++cf) {
                int n = wn * 64 + cf * 16 + l15;
                float bv = bias[n0 + n];
#pragma unroll
                for (int rf = 0; rf < 4; ++rf) {
                    int m = wm * 64 + rf * 16 + quad * 4;   // m&7 in {0,4} -> 8B aligned
                    half4_t h4;
#pragma unroll
                    for (int r = 0; r < 4; ++r) h4[r] = (_Float16)(acc[rf][cf][r] + bv);
                    *(half4_t*)(lds + n * 528 + ((m >> 3) << 4) + (m & 7) * 2) = h4;
                }
            }
            __syncthreads();
            // readback: lanes sweep l15v (d&15) -> 16B-contig chunks; wave covers 1KB
            int l15v = tid & 15;
            int moct = W * 4 + ((tid >> 4) & 3);     // m-octet 0..31
            int t = tb + moct * 8;
            int kbv = (t >> 5) & 31, quad_v = (t >> 3) & 3;
#pragma unroll
            for (int i = 0; i < 8; ++i) {
                int hh = i >> 2, cf = i & 3;
                int n = hh * 64 + cf * 16 + l15v;
                half8 v = *(const half8*)(lds + n * 528 + (moct << 4));
                int gcol = nb + n;
                int h = gcol >> 6, d = gcol & 63;
                size_t chunk = (size_t)((b * 16 + h) * 32 + kbv) * 256 +
                               (d >> 4) * 64 + quad_v * 16 + (d & 15);
                *(half8*)(vPo + chunk * 8) = v;
            }
        } else {
            // Q/K: stage [m=256][n=128], row stride 272B (68 words % 32 = 4)
#pragma unroll
            for (int cf = 0; cf < 4; ++cf) {
                int n = wn * 64 + cf * 16 + l15;
                float bv = bias[n0 + n];
                int nbyte = ((n >> 3) << 4) + (n & 7) * 2;
#pragma unroll
                for (int rf = 0; rf < 4; ++rf) {
                    int m = wm * 64 + rf * 16 + quad * 4;
#pragma unroll
                    for (int r = 0; r < 4; ++r)
                        *(_Float16*)(lds + (m + r) * 272 + nbyte) =
                            (_Float16)(acc[rf][cf][r] + bv);
                }
            }
            __syncthreads();
            if (sec == 0) {
                // Q rows: lanes sweep noct -> 256B contiguous per 16 lanes
                int noct = tid & 15;
#pragma unroll
                for (int i = 0; i < 8; ++i) {
                    int m = i * 32 + (tid >> 4);
                    half8 v = *(const half8*)(lds + m * 272 + (noct << 4));
                    *(half8*)(qno + (size_t)(b * 1024 + tb + m) * 1024 + nb + noct * 8) = v;
                }
            } else {
                // K packed: lanes sweep l15k (t&15) -> 16B steps; wave covers 1KB
                int l15k = tid & 15, noct = (tid >> 4) & 15;
#pragma unroll
                for (int i = 0; i < 8; ++i) {
                    int mb = i * 2 + (tid >> 8);
                    int m = mb * 16 + l15k;
                    half8 v = *(const half8*)(lds + m * 272 + (noct << 4));
                    int gcol = nb + noct * 8;
                    int h = gcol >> 6, d0 = gcol & 63;
                    int t = tb + m;
                    size_t chunk = (size_t)((b * 16 + h) * 64 + (t >> 4)) * 128 +
                                   (d0 >> 5) * 64 + ((d0 >> 3) & 3) * 16 + l15k;
                    *(half8*)(kPo + chunk * 8) = v;
                }
            }
        }
    }
}

// ------------------------------- attention v6 + XCD swizzle -------------------------------
// grid 4096 blocks (32 q-tiles x 128 bh), 512 threads = 8 waves.
// Wave w owns k-slice [w*128, w*128+128).
// XCD swizzle (r3-proven): XCD i gets bh in [i*16,(i+1)*16) -> K/V (4MB) fits its L2.
// LDS: E = 32 q-rows x 1024 k fp16 (64KB), xor-swizzled 16B granules; lsum 8x32 f32.
__device__ __forceinline__ int esw(int row, int colByte) {
    return row * 2048 + (colByte ^ ((row & 7) << 4));
}

__global__ __launch_bounds__(512, 4) void attn(const _Float16* __restrict__ qn,
                                               const _Float16* __restrict__ kP,
                                               const _Float16* __restrict__ vP,
                                               _Float16* __restrict__ y) {
    __shared__ __attribute__((aligned(16))) _Float16 E[32 * 1024];
    __shared__ float lsum[8][32];
    char* Eb = (char*)E;
    int tid = threadIdx.x;
    int W = tid >> 6, lane = tid & 63, quad = lane >> 4, l15 = lane & 15;
    int flat = blockIdx.y * 32 + blockIdx.x;
    int swz = (flat & 7) * 512 + (flat >> 3);     // bijective, 4096 % 8 == 0
    int qt = swz & 31, bh = swz >> 5;
    int b = bh >> 4, h = bh & 15;
    int q0 = qt * 32;

    // --- Q as B-fragments (B[k=quad*8+j][n=l15]): n = q-row, k = d ---
    half8 bq[2][2];
#pragma unroll
    for (int nf = 0; nf < 2; ++nf)
#pragma unroll
        for (int ks = 0; ks < 2; ++ks)
            bq[nf][ks] = *(const half8*)(qn + (size_t)(b * 1024 + q0 + nf * 16 + l15) * 1024 +
                                         h * 64 + ks * 32 + quad * 8);

    // --- Phase 1: S^T = K.Q^T (scaled), e = exp(s) -> E; rowsum partials in regs ---
    float lpart[2] = {0.f, 0.f};
#pragma unroll 4
    for (int mt = 0; mt < 8; ++mt) {
        int kb = W * 8 + mt;
        const _Float16* kp = kP + ((size_t)(bh * 64 + kb) * 128 + lane) * 8;
        half8 ak0 = *(const half8*)(kp);            // contiguous 1KB per wave
        half8 ak1 = *(const half8*)(kp + 512);
#pragma unroll
        for (int nf = 0; nf < 2; ++nf) {
            floatx4 s = {};
            s = __builtin_amdgcn_mfma_f32_16x16x32_f16(ak0, bq[nf][0], s, 0, 0, 0);
            s = __builtin_amdgcn_mfma_f32_16x16x32_f16(ak1, bq[nf][1], s, 0, 0, 0);
            half4_t h4;
#pragma unroll
            for (int r = 0; r < 4; ++r) {
                float e = __expf(fminf(s[r] * 0.125f, 10.0f));  // exp(10)=22026 < fp16 max
                lpart[nf] += e;
                h4[r] = (_Float16)e;
            }
            int q = nf * 16 + l15;
            int kbyte = (W * 128 + mt * 16 + quad * 4) * 2;
            *(half4_t*)(Eb + q * 2048 + (kbyte ^ ((q & 7) << 4))) = h4;
        }
    }
    // reduce over the 4 quads (lanes sharing l15)
#pragma unroll
    for (int nf = 0; nf < 2; ++nf) {
        lpart[nf] += __shfl_xor(lpart[nf], 16);
        lpart[nf] += __shfl_xor(lpart[nf], 32);
    }
    if (lane < 16) {
        lsum[W][l15] = lpart[0];
        lsum[W][16 + l15] = lpart[1];
    }
    __syncthreads();

    // --- Phase 2: PV over wave's k-slice; normalize+threshold fused in regs ---
    half8 inv8[2], t8, z8;
#pragma unroll
    for (int j = 0; j < 8; ++j) { t8[j] = (_Float16)(-0.001f); z8[j] = (_Float16)0.f; }
#pragma unroll
    for (int rf = 0; rf < 2; ++rf) {
        float l = 0.f;
#pragma unroll
        for (int w = 0; w < 8; ++w) l += lsum[w][rf * 16 + l15];
        _Float16 invh = (_Float16)(1.0f / l);
#pragma unroll
        for (int j = 0; j < 8; ++j) inv8[rf][j] = invh;
    }

    floatx4 acc[2][4] = {};
#pragma unroll
    for (int kt = 0; kt < 4; ++kt) {
        int kk = W * 128 + kt * 32;
        half8 ap[2];
#pragma unroll
        for (int rf = 0; rf < 2; ++rf) {
            ap[rf] = *(const half8*)(Eb + esw(rf * 16 + l15, (kk + quad * 8) * 2));
            ap[rf] = ap[rf] * inv8[rf] + t8;                        // v_pk_fma_f16
            ap[rf] = __builtin_elementwise_max(ap[rf], z8);         // v_pk_max_f16
        }
        const _Float16* vbase = vP + ((size_t)(bh * 32 + (W * 4 + kt)) * 256 + lane) * 8;
        half8 bv[4];
#pragma unroll
        for (int cf = 0; cf < 4; ++cf)
            bv[cf] = *(const half8*)(vbase + cf * 512);             // contiguous 1KB / wave
#pragma unroll
        for (int rf = 0; rf < 2; ++rf)
#pragma unroll
            for (int cf = 0; cf < 4; ++cf)
                acc[rf][cf] = __builtin_amdgcn_mfma_f32_16x16x32_f16(ap[rf], bv[cf], acc[rf][cf], 0, 0, 0);
    }
    __syncthreads();   // all waves done reading E before reuse

    // --- Phase 3: LDS-reduce the 8 k-slice partials (reuse E: 8x32x64 f32 = 64KB) ---
    float* red = (float*)E;
#pragma unroll
    for (int rf = 0; rf < 2; ++rf)
#pragma unroll
        for (int cf = 0; cf < 4; ++cf)
#pragma unroll
            for (int r = 0; r < 4; ++r)
                red[W * 2048 + (rf * 16 + quad * 4 + r) * 64 + cf * 16 + l15] = acc[rf][cf][r];
    __syncthreads();
    {
        int e4 = tid * 4;                 // 512 thr x 4 = 2048 = 32x64
        int r = e4 >> 6, c = e4 & 63;
        floatx4 s = {};
#pragma unroll
        for (int w = 0; w < 8; ++w) s += *(const floatx4*)(red + w * 2048 + e4);
        half4_t hv = { (_Float16)s[0], (_Float16)s[1], (_Float16)s[2], (_Float16)s[3] };
        *(half4_t*)(y + (size_t)(b * 1024 + q0 + r) * 1024 + h * 64 + c) = hv;
    }
}

// ------------------------------- launcher -------------------------------
extern "C" void kernel_launch(void* const* d_in, const int* in_sizes, int n_in,
                              void* d_out, int out_size, void* d_ws, size_t ws_size,
                              hipStream_t stream) {
    const float* x  = (const float*)d_in[0];
    const float* wa = (const float*)d_in[1];
    const float* ba = (const float*)d_in[2];
    const float* wp = (const float*)d_in[3];
    const float* bp = (const float*)d_in[4];
    float* out = (float*)d_out;

    char* ws = (char*)d_ws;
    _Float16* y   = (_Float16*)(ws);                    // [0,16M)   attn out
    _Float16* qn  = (_Float16*)(ws + 16777216);         // [16M,32M)
    _Float16* kP  = (_Float16*)(ws + 33554432);         // [32M,48M)
    _Float16* vP  = (_Float16*)(ws + 50331648);         // [48M,64M)
    _Float16* waT = (_Float16*)(ws + 67108864);         // [64M,70M)
    _Float16* wpT = (_Float16*)(ws + 73400320);         // [70M,72M)
    _Float16* xh  = (_Float16*)(ws + 75497472);         // [72M,88M) dead after gemm1

    conv_x<<<4096, 256, 0, stream>>>((const float4*)x, xh, 8388608 / 4);
    tconv<<<dim3(48, 16), 256, 0, stream>>>(wa, waT, 1024, 3072);
    tconv<<<dim3(16, 16), 256, 0, stream>>>(wp, wpT, 1024, 1024);
    gemm8p<true><<<dim3(24, 32), 512, 0, stream>>>(xh, waT, ba, (void*)qn, (void*)kP, (void*)vP, 3072);
    attn<<<dim3(32, 128), 512, 0, stream>>>(qn, kP, vP, y);
    gemm8p<false><<<dim3(8, 32), 512, 0, stream>>>(y, wpT, bp, (void*)out, nullptr, nullptr, 1024);
}

// Round 5
// 258.306 us; speedup vs baseline: 1.1554x; 1.0074x over previous
//
#include <hip/hip_runtime.h>

// TreeAttentionV2: B=8, T=1024, C=1024 (L=4,R=256), H=16, hd=64.
// Pipeline (all fp16 MFMA, fp32 accumulate):
//   1. conv_x:    x fp32 (8192x1024) -> xh fp16
//   2. tconv2:    w_attn -> waT fp16 (3072x1024) AND w_proj -> wpT (1024x1024), one launch
//   3. gemm_qkv:  qn/kP/vP = xh @ waT^T + b_attn. 256x256x64 8-phase (m201 geometry,
//                 16 MFMA/phase, 128KB LDS, 1 block/CU); fused-pack epilogue in two
//                 column-half passes (Q rows / K A-frag chunks / V^T B-frag chunks).
//   4. attn v6+s: 32-row q-tile, 8 waves, k-sliced + XCD-swizzled grid; exp2-direct.
//   5. gemm_proj: out = y @ wpT^T + b_proj (proven narrow 256x128 8-phase, 1 exact round)
//
// Workspace (88 MiB):
//   [0,16M)   y    (attn output; region free until attn)
//   [16M,32M) qn ; [32M,48M) kP ; [48M,64M) vP
//   [64M,70M) waT ; [70M,72M) wpT ; [72M,88M) xh (dead after gemm_qkv)

typedef _Float16 half8 __attribute__((ext_vector_type(8)));
typedef _Float16 half4_t __attribute__((ext_vector_type(4)));
typedef float floatx4 __attribute__((ext_vector_type(4)));

__device__ __forceinline__ void gl2lds16(const void* gsrc, void* lds) {
    __builtin_amdgcn_global_load_lds(
        (const __attribute__((address_space(1))) unsigned int*)gsrc,
        (__attribute__((address_space(3))) unsigned int*)lds,
        16, 0, 0);
}

// ---------------- elementwise convert fp32 -> fp16 ----------------
__global__ __launch_bounds__(256) void conv_x(const float4* __restrict__ in,
                                              _Float16* __restrict__ out, int n4) {
    int idx = blockIdx.x * blockDim.x + threadIdx.x;
    int stride = gridDim.x * blockDim.x;
    for (int i = idx; i < n4; i += stride) {
        float4 v = in[i];
        half4_t h = { (_Float16)v.x, (_Float16)v.y, (_Float16)v.z, (_Float16)v.w };
        *(half4_t*)(out + (size_t)i * 4) = h;
    }
}

// ------------- transpose + convert both weights: out[n][k] = in[k][n] ----------
__global__ __launch_bounds__(256) void tconv2(const float* __restrict__ wa,
                                              _Float16* __restrict__ waT,
                                              const float* __restrict__ wp,
                                              _Float16* __restrict__ wpT) {
    __shared__ _Float16 t[64 * 65];
    int bx = blockIdx.x, by = blockIdx.y;
    const float* in = wa; _Float16* out = waT; int C = 3072;
    if (bx >= 48) { bx -= 48; in = wp; out = wpT; C = 1024; }
#pragma unroll
    for (int it = 0; it < 16; ++it) {
        int idx = it * 256 + threadIdx.x;
        int r = idx >> 6, c = idx & 63;
        t[c * 65 + r] = (_Float16)in[(size_t)(by * 64 + r) * C + bx * 64 + c];
    }
    __syncthreads();
#pragma unroll
    for (int it = 0; it < 16; ++it) {
        int idx = it * 256 + threadIdx.x;
        int rn = idx >> 6, ck = idx & 63;
        out[(size_t)(bx * 64 + rn) * 1024 + by * 64 + ck] = t[rn * 65 + ck];
    }
}

// common pipeline helpers
#define GBAR __builtin_amdgcn_s_barrier()
#define WLGKM do { asm volatile("s_waitcnt lgkmcnt(0)" ::: "memory"); } while (0)
#define WVM2  do { asm volatile("s_waitcnt vmcnt(2)"   ::: "memory"); } while (0)
#define WVM4  do { asm volatile("s_waitcnt vmcnt(4)"   ::: "memory"); } while (0)
#define WVM0  do { asm volatile("s_waitcnt vmcnt(0)"   ::: "memory"); } while (0)

// ================= gemm_qkv: 256x256 8-phase (m201 geometry) + fused-pack epilogue ======
// BM=256, BN=256, BK=64, K=1024. 512 threads = 8 waves (2M x 4N), per-wave 128x64.
// LDS 128KB: sA 2buf x 32KB @0, sB 2buf x 32KB @65536. XOR-swizzle via inverse-swizzled
// global source (rule #21). Per phase: one C-quadrant (4x2 frags x K=64) = 16 MFMA,
// plus one half-tile stage (2 gl2lds16/thread). Counted vmcnt: WVM4 at P4/P8 only.
// kP chunk c holds K[t=(c>>7&63)*16+(c&15)][d=(c>>6&1)*32+((c>>4)&3)*8+j]  (c per bh<<13)
// vP chunk c holds V^T[d=((c&255)>>6)*16+(c&15)][k=(c>>8&31)*32+((c>>4)&3)*8+j] (per bh<<13)

#define WLDA(buf, rg)                                                                         \
    do {                                                                                      \
        _Pragma("unroll") for (int i = 0; i < 4; ++i) {                                       \
            int r_ = wm * 128 + ((rg) * 4 + i) * 16 + l15;                                    \
            _Pragma("unroll") for (int kk = 0; kk < 2; ++kk)                                  \
                a[i][kk] = *(const half8*)(sA + (buf) * 32768 + r_ * 128 +                    \
                                           ((((kk << 2) + quad) ^ (r_ & 7)) << 4));           \
        }                                                                                     \
    } while (0)

#define WLDB(buf, cg, bb)                                                                     \
    do {                                                                                      \
        _Pragma("unroll") for (int j = 0; j < 2; ++j) {                                       \
            int r_ = wn * 64 + ((cg) * 2 + j) * 16 + l15;                                     \
            _Pragma("unroll") for (int kk = 0; kk < 2; ++kk)                                  \
                bb[j][kk] = *(const half8*)(sB + (buf) * 32768 + r_ * 128 +                   \
                                            ((((kk << 2) + quad) ^ (r_ & 7)) << 4));          \
        }                                                                                     \
    } while (0)

#define WMMA(rg, cg, bb)                                                                      \
    do {                                                                                      \
        __builtin_amdgcn_s_setprio(1);                                                        \
        _Pragma("unroll") for (int kk = 0; kk < 2; ++kk)                                      \
            _Pragma("unroll") for (int i = 0; i < 4; ++i)                                     \
                _Pragma("unroll") for (int j = 0; j < 2; ++j)                                  \
                    acc[(rg) * 4 + i][(cg) * 2 + j] = __builtin_amdgcn_mfma_f32_16x16x32_f16( \
                        a[i][kk], bb[j][kk], acc[(rg) * 4 + i][(cg) * 2 + j], 0, 0, 0);       \
        __builtin_amdgcn_s_setprio(0);                                                        \
    } while (0)

__global__ __launch_bounds__(512, 2) void gemm_qkv(const _Float16* __restrict__ A,
                                                   const _Float16* __restrict__ BT,
                                                   const float* __restrict__ bias,
                                                   _Float16* __restrict__ qno,
                                                   _Float16* __restrict__ kPo,
                                                   _Float16* __restrict__ vPo) {
    __shared__ __attribute__((aligned(16))) char lds[131072];
    char* sA = lds;           // + buf*32768 + half*16384 + rnd*8192
    char* sB = lds + 65536;
    int tid = threadIdx.x;
    int W = tid >> 6, lane = tid & 63, quad = lane >> 4, l15 = lane & 15;
    int wm = W >> 2, wn = W & 3;
    int m0 = blockIdx.y * 256, n0 = blockIdx.x * 256;

    auto stA = [&](int buf, int half, int k0) {
#pragma unroll
        for (int rnd = 0; rnd < 2; ++rnd) {
            int c = rnd * 512 + tid;
            int row = c >> 3;
            int q = (c & 7) ^ (row & 7);
            const _Float16* src = A + (size_t)(m0 + half * 128 + row) * 1024 + k0 + q * 8;
            int off = __builtin_amdgcn_readfirstlane(buf * 32768 + half * 16384 +
                                                     rnd * 8192 + (W << 10));
            gl2lds16(src, sA + off);
        }
    };
    auto stB = [&](int buf, int half, int k0) {
#pragma unroll
        for (int rnd = 0; rnd < 2; ++rnd) {
            int c = rnd * 512 + tid;
            int row = c >> 3;
            int q = (c & 7) ^ (row & 7);
            const _Float16* src = BT + (size_t)(n0 + half * 128 + row) * 1024 + k0 + q * 8;
            int off = __builtin_amdgcn_readfirstlane(buf * 32768 + half * 16384 +
                                                     rnd * 8192 + (W << 10));
            gl2lds16(src, sB + off);
        }
    };

    half8 a[4][2], b0[2][2], b1[2][2];
    floatx4 acc[8][4] = {};

    // prologue: A(0),B(0) -> buf0 (8 loads); B(1) -> buf1 (4 loads, left in flight)
    stA(0, 0, 0); stA(0, 1, 0);
    stB(0, 0, 0); stB(0, 1, 0);
    stB(1, 0, 64); stB(1, 1, 64);
    WVM4;
    GBAR;

#pragma unroll 1
    for (int t = 0; t < 16; t += 2) {
        int k1 = (t + 1) << 6;
        int k2 = ((t + 2) & 15) << 6;   // wraps last iter: garbage into dead bufs
        int k3 = ((t + 3) & 15) << 6;
        // ---- tile t (buf0) ----
        WLDA(0, 0); WLDB(0, 0, b0); stA(1, 0, k1);
        GBAR; WLGKM; WMMA(0, 0, b0); GBAR;                 // P1
        WLDB(0, 1, b1); stA(1, 1, k1);
        GBAR; WLGKM; WMMA(0, 1, b1); GBAR;                 // P2
        WLDA(0, 1); stB(0, 0, k2);
        GBAR; WLGKM; WMMA(1, 1, b1); GBAR;                 // P3
        stB(0, 1, k2); WVM4;
        GBAR; WLGKM; WMMA(1, 0, b0); GBAR;                 // P4
        // ---- tile t+1 (buf1) ----
        WLDA(1, 0); WLDB(1, 0, b0); stA(0, 0, k2);
        GBAR; WLGKM; WMMA(0, 0, b0); GBAR;                 // P5
        WLDB(1, 1, b1); stA(0, 1, k2);
        GBAR; WLGKM; WMMA(0, 1, b1); GBAR;                 // P6
        WLDA(1, 1); stB(1, 0, k3);
        GBAR; WLGKM; WMMA(1, 1, b1); GBAR;                 // P7
        stB(1, 1, k3); WVM4;
        GBAR; WLGKM; WMMA(1, 0, b0); GBAR;                 // P8
    }

    // ---- fused-pack epilogue: two column-half passes (128 cols each) ----
    WVM0;          // trailing prefetch DMA must land before LDS reuse
    GBAR;
    int sec = n0 >> 10;          // 0=Q 1=K 2=V (256-tiles never straddle 1024)
    int b = m0 >> 10;            // batch (BM=256 stays within one b)
    int tb = m0 & 1023;          // token base
#pragma unroll 1
    for (int p = 0; p < 2; ++p) {
        if (p) __syncthreads();          // pass-0 reads done before restage
        if (sec == 2) {
            // V: stage transposed [lc=128][m=256], row stride 528B
            if ((wn >> 1) == p) {
#pragma unroll
                for (int cf = 0; cf < 4; ++cf) {
                    int lc = (wn & 1) * 64 + cf * 16 + l15;
                    float bv = bias[n0 + wn * 64 + cf * 16 + l15];
#pragma unroll
                    for (int rf = 0; rf < 8; ++rf) {
                        int m = wm * 128 + rf * 16 + quad * 4;   // m&7 in {0,4}: 8B aligned
                        half4_t h4;
#pragma unroll
                        for (int r = 0; r < 4; ++r) h4[r] = (_Float16)(acc[rf][cf][r] + bv);
                        *(half4_t*)(lds + lc * 528 + m * 2) = h4;
                    }
                }
            }
            __syncthreads();
            int l15v = tid & 15;
            int moct = W * 4 + ((tid >> 4) & 3);     // m-octet 0..31
            int t = tb + moct * 8;
            int kbv = (t >> 5) & 31, quad_v = (t >> 3) & 3;
            int nbV = (n0 & 1023) + p * 128;
#pragma unroll
            for (int i = 0; i < 8; ++i) {
                int hh = i >> 2, cf = i & 3;
                int n = hh * 64 + cf * 16 + l15v;
                half8 v = *(const half8*)(lds + n * 528 + (moct << 4));
                int gcol = nbV + n;
                int h = gcol >> 6, d = gcol & 63;
                size_t chunk = (size_t)((b * 16 + h) * 32 + kbv) * 256 +
                               (d >> 4) * 64 + quad_v * 16 + (d & 15);
                *(half8*)(vPo + chunk * 8) = v;
            }
        } else {
            // Q/K: stage [m=256][lc=128], row stride 272B
            if ((wn >> 1) == p) {
#pragma unroll
                for (int cf = 0; cf < 4; ++cf) {
                    int lc = (wn & 1) * 64 + cf * 16 + l15;
                    float bv = bias[n0 + wn * 64 + cf * 16 + l15];
#pragma unroll
                    for (int rf = 0; rf < 8; ++rf) {
                        int m = wm * 128 + rf * 16 + quad * 4;
#pragma unroll
                        for (int r = 0; r < 4; ++r)
                            *(_Float16*)(lds + (m + r) * 272 + lc * 2) =
                                (_Float16)(acc[rf][cf][r] + bv);
                    }
                }
            }
            __syncthreads();
            int nb = (n0 & 1023) + p * 128;
            if (sec == 0) {
                int noct = tid & 15;
#pragma unroll
                for (int i = 0; i < 8; ++i) {
                    int m = i * 32 + (tid >> 4);
                    half8 v = *(const half8*)(lds + m * 272 + (noct << 4));
                    *(half8*)(qno + (size_t)(b * 1024 + tb + m) * 1024 + nb + noct * 8) = v;
                }
            } else {
                int l15k = tid & 15, noct = (tid >> 4) & 15;
#pragma unroll
                for (int i = 0; i < 8; ++i) {
                    int mb = i * 2 + (tid >> 8);
                    int m = mb * 16 + l15k;
                    half8 v = *(const half8*)(lds + m * 272 + (noct << 4));
                    int gcol = nb + noct * 8;
                    int h = gcol >> 6, d0 = gcol & 63;
                    int t = tb + m;
                    size_t chunk = (size_t)((b * 16 + h) * 64 + (t >> 4)) * 128 +
                                   (d0 >> 5) * 64 + ((d0 >> 3) & 3) * 16 + l15k;
                    *(half8*)(kPo + chunk * 8) = v;
                }
            }
        }
    }
}

// ================= gemm_proj: narrow 256x128 8-phase (proven), f32 out =================
#define LDA(buf, rg)                                                                          \
    do {                                                                                      \
        _Pragma("unroll") for (int i = 0; i < 2; ++i) {                                       \
            int r_ = wm * 64 + ((rg) * 2 + i) * 16 + l15;                                     \
            _Pragma("unroll") for (int kk = 0; kk < 2; ++kk)                                  \
                a[i][kk] = *(const half8*)(sA + (buf) * 32768 + r_ * 128 +                    \
                                           ((((kk << 2) + quad) ^ (r_ & 7)) << 4));           \
        }                                                                                     \
    } while (0)

#define LDB(buf, cg, bb)                                                                      \
    do {                                                                                      \
        _Pragma("unroll") for (int j = 0; j < 2; ++j) {                                       \
            int r_ = wn * 64 + ((cg) * 2 + j) * 16 + l15;                                     \
            _Pragma("unroll") for (int kk = 0; kk < 2; ++kk)                                  \
                bb[j][kk] = *(const half8*)(sB + (buf) * 16384 + r_ * 128 +                   \
                                            ((((kk << 2) + quad) ^ (r_ & 7)) << 4));          \
        }                                                                                     \
    } while (0)

#define MMA(rg, cg, bb)                                                                       \
    do {                                                                                      \
        __builtin_amdgcn_s_setprio(1);                                                        \
        _Pragma("unroll") for (int kk = 0; kk < 2; ++kk)                                      \
            _Pragma("unroll") for (int i = 0; i < 2; ++i)                                     \
                _Pragma("unroll") for (int j = 0; j < 2; ++j)                                  \
                    acc[(rg) * 2 + i][(cg) * 2 + j] = __builtin_amdgcn_mfma_f32_16x16x32_f16( \
                        a[i][kk], bb[j][kk], acc[(rg) * 2 + i][(cg) * 2 + j], 0, 0, 0);       \
        __builtin_amdgcn_s_setprio(0);                                                        \
    } while (0)

__global__ __launch_bounds__(512, 2) void gemm_proj(const _Float16* __restrict__ A,
                                                    const _Float16* __restrict__ BT,
                                                    const float* __restrict__ bias,
                                                    float* __restrict__ o0, int N) {
    __shared__ __attribute__((aligned(16))) char lds[98304];
    char* sA = lds;
    char* sB = lds + 65536;
    int tid = threadIdx.x;
    int W = tid >> 6, lane = tid & 63, quad = lane >> 4, l15 = lane & 15;
    int wm = W >> 1, wn = W & 1;
    int m0 = blockIdx.y * 256, n0 = blockIdx.x * 128;

    auto stA = [&](int buf, int half, int k0) {
#pragma unroll
        for (int rnd = 0; rnd < 2; ++rnd) {
            int c = rnd * 512 + tid;
            int row = c >> 3;
            int q = (c & 7) ^ (row & 7);
            const _Float16* src = A + (size_t)(m0 + half * 128 + row) * 1024 + k0 + q * 8;
            int off = __builtin_amdgcn_readfirstlane(buf * 32768 + half * 16384 +
                                                     rnd * 8192 + (W << 10));
            gl2lds16(src, sA + off);
        }
    };
    auto stB = [&](int buf, int half, int k0) {
        int row = tid >> 3;
        int q = (tid & 7) ^ (row & 7);
        const _Float16* src = BT + (size_t)(n0 + half * 64 + row) * 1024 + k0 + q * 8;
        int off = __builtin_amdgcn_readfirstlane(buf * 16384 + half * 8192 + (W << 10));
        gl2lds16(src, sB + off);
    };

    half8 a[2][2], b0[2][2], b1[2][2];
    floatx4 acc[4][4] = {};

    stA(0, 0, 0); stA(0, 1, 0);
    stB(0, 0, 0); stB(0, 1, 0);
    stB(1, 0, 64); stB(1, 1, 64);
    WVM2;
    GBAR;

#pragma unroll 1
    for (int t = 0; t < 16; t += 2) {
        int k1 = (t + 1) << 6;
        int k2 = ((t + 2) & 15) << 6;
        int k3 = ((t + 3) & 15) << 6;
        LDA(0, 0); LDB(0, 0, b0); stA(1, 0, k1);
        GBAR; WLGKM; MMA(0, 0, b0); GBAR;
        LDB(0, 1, b1); stA(1, 1, k1);
        GBAR; WLGKM; MMA(0, 1, b1); GBAR;
        LDA(0, 1); stB(0, 0, k2);
        GBAR; WLGKM; MMA(1, 1, b1); GBAR;
        stB(0, 1, k2); WVM2;
        GBAR; WLGKM; MMA(1, 0, b0); GBAR;
        LDA(1, 0); LDB(1, 0, b0); stA(0, 0, k2);
        GBAR; WLGKM; MMA(0, 0, b0); GBAR;
        LDB(1, 1, b1); stA(0, 1, k2);
        GBAR; WLGKM; MMA(0, 1, b1); GBAR;
        LDA(1, 1); stB(1, 0, k3);
        GBAR; WLGKM; MMA(1, 1, b1); GBAR;
        stB(1, 1, k3); WVM2;
        GBAR; WLGKM; MMA(1, 0, b0); GBAR;
    }

#pragma unroll
    for (int cf = 0; cf < 4; ++cf) {
        int gn = n0 + wn * 64 + cf * 16 + l15;
        float bv = bias[gn];
#pragma unroll
        for (int rf = 0; rf < 4; ++rf) {
            int gmBase = m0 + wm * 64 + rf * 16 + quad * 4;
#pragma unroll
            for (int r = 0; r < 4; ++r)
                o0[(size_t)(gmBase + r) * N + gn] = acc[rf][cf][r] + bv;
        }
    }
}

// ------------------------------- attention v6 + XCD swizzle -------------------------------
// grid 4096 blocks (32 q-tiles x 128 bh), 512 threads = 8 waves.
// Wave w owns k-slice [w*128, w*128+128).
// XCD swizzle (r3/r4-proven): each bh's 32 q-tiles share one XCD L2 (FETCH 139->25MB).
// LDS: E = 32 q-rows x 1024 k fp16 (64KB), xor-swizzled 16B granules; lsum 8x32 f32.
__device__ __forceinline__ int esw(int row, int colByte) {
    return row * 2048 + (colByte ^ ((row & 7) << 4));
}

__global__ __launch_bounds__(512, 4) void attn(const _Float16* __restrict__ qn,
                                               const _Float16* __restrict__ kP,
                                               const _Float16* __restrict__ vP,
                                               _Float16* __restrict__ y) {
    __shared__ __attribute__((aligned(16))) _Float16 E[32 * 1024];
    __shared__ float lsum[8][32];
    char* Eb = (char*)E;
    int tid = threadIdx.x;
    int W = tid >> 6, lane = tid & 63, quad = lane >> 4, l15 = lane & 15;
    int flat = blockIdx.y * 32 + blockIdx.x;
    int swz = (flat & 7) * 512 + (flat >> 3);     // bijective, 4096 % 8 == 0
    int qt = swz & 31, bh = swz >> 5;
    int b = bh >> 4, h = bh & 15;
    int q0 = qt * 32;

    // --- Q as B-fragments (B[k=quad*8+j][n=l15]): n = q-row, k = d ---
    half8 bq[2][2];
#pragma unroll
    for (int nf = 0; nf < 2; ++nf)
#pragma unroll
        for (int ks = 0; ks < 2; ++ks)
            bq[nf][ks] = *(const half8*)(qn + (size_t)(b * 1024 + q0 + nf * 16 + l15) * 1024 +
                                         h * 64 + ks * 32 + quad * 8);

    // --- Phase 1: S^T = K.Q^T, e = exp2(s*c) -> E; rowsum partials in regs ---
    float lpart[2] = {0.f, 0.f};
#pragma unroll 4
    for (int mt = 0; mt < 8; ++mt) {
        int kb = W * 8 + mt;
        const _Float16* kp = kP + ((size_t)(bh * 64 + kb) * 128 + lane) * 8;
        half8 ak0 = *(const half8*)(kp);            // contiguous 1KB per wave
        half8 ak1 = *(const half8*)(kp + 512);
#pragma unroll
        for (int nf = 0; nf < 2; ++nf) {
            floatx4 s = {};
            s = __builtin_amdgcn_mfma_f32_16x16x32_f16(ak0, bq[nf][0], s, 0, 0, 0);
            s = __builtin_amdgcn_mfma_f32_16x16x32_f16(ak1, bq[nf][1], s, 0, 0, 0);
            half4_t h4;
#pragma unroll
            for (int r = 0; r < 4; ++r) {
                // exp(min(s/8,10)) == exp2(min(s*0.125*log2e, 14.4269504))
                float e = __builtin_amdgcn_exp2f(fminf(s[r] * 0.18033688f, 14.4269504f));
                lpart[nf] += e;
                h4[r] = (_Float16)e;
            }
            int q = nf * 16 + l15;
            int kbyte = (W * 128 + mt * 16 + quad * 4) * 2;
            *(half4_t*)(Eb + q * 2048 + (kbyte ^ ((q & 7) << 4))) = h4;
        }
    }
    // reduce over the 4 quads (lanes sharing l15)
#pragma unroll
    for (int nf = 0; nf < 2; ++nf) {
        lpart[nf] += __shfl_xor(lpart[nf], 16);
        lpart[nf] += __shfl_xor(lpart[nf], 32);
    }
    if (lane < 16) {
        lsum[W][l15] = lpart[0];
        lsum[W][16 + l15] = lpart[1];
    }
    __syncthreads();

    // --- Phase 2: PV over wave's k-slice; normalize+threshold fused in regs ---
    half8 inv8[2], t8, z8;
#pragma unroll
    for (int j = 0; j < 8; ++j) { t8[j] = (_Float16)(-0.001f); z8[j] = (_Float16)0.f; }
#pragma unroll
    for (int rf = 0; rf < 2; ++rf) {
        float l = 0.f;
#pragma unroll
        for (int w = 0; w < 8; ++w) l += lsum[w][rf * 16 + l15];
        _Float16 invh = (_Float16)(1.0f / l);
#pragma unroll
        for (int j = 0; j < 8; ++j) inv8[rf][j] = invh;
    }

    floatx4 acc[2][4] = {};
#pragma unroll
    for (int kt = 0; kt < 4; ++kt) {
        int kk = W * 128 + kt * 32;
        half8 ap[2];
#pragma unroll
        for (int rf = 0; rf < 2; ++rf) {
            ap[rf] = *(const half8*)(Eb + esw(rf * 16 + l15, (kk + quad * 8) * 2));
            ap[rf] = ap[rf] * inv8[rf] + t8;                        // v_pk_fma_f16
            ap[rf] = __builtin_elementwise_max(ap[rf], z8);         // v_pk_max_f16
        }
        const _Float16* vbase = vP + ((size_t)(bh * 32 + (W * 4 + kt)) * 256 + lane) * 8;
        half8 bv[4];
#pragma unroll
        for (int cf = 0; cf < 4; ++cf)
            bv[cf] = *(const half8*)(vbase + cf * 512);             // contiguous 1KB / wave
#pragma unroll
        for (int rf = 0; rf < 2; ++rf)
#pragma unroll
            for (int cf = 0; cf < 4; ++cf)
                acc[rf][cf] = __builtin_amdgcn_mfma_f32_16x16x32_f16(ap[rf], bv[cf], acc[rf][cf], 0, 0, 0);
    }
    __syncthreads();   // all waves done reading E before reuse

    // --- Phase 3: LDS-reduce the 8 k-slice partials (reuse E: 8x32x64 f32 = 64KB) ---
    float* red = (float*)E;
#pragma unroll
    for (int rf = 0; rf < 2; ++rf)
#pragma unroll
        for (int cf = 0; cf < 4; ++cf)
#pragma unroll
            for (int r = 0; r < 4; ++r)
                red[W * 2048 + (rf * 16 + quad * 4 + r) * 64 + cf * 16 + l15] = acc[rf][cf][r];
    __syncthreads();
    {
        int e4 = tid * 4;                 // 512 thr x 4 = 2048 = 32x64
        int r = e4 >> 6, c = e4 & 63;
        floatx4 s = {};
#pragma unroll
        for (int w = 0; w < 8; ++w) s += *(const floatx4*)(red + w * 2048 + e4);
        half4_t hv = { (_Float16)s[0], (_Float16)s[1], (_Float16)s[2], (_Float16)s[3] };
        *(half4_t*)(y + (size_t)(b * 1024 + q0 + r) * 1024 + h * 64 + c) = hv;
    }
}

// ------------------------------- launcher -------------------------------
extern "C" void kernel_launch(void* const* d_in, const int* in_sizes, int n_in,
                              void* d_out, int out_size, void* d_ws, size_t ws_size,
                              hipStream_t stream) {
    const float* x  = (const float*)d_in[0];
    const float* wa = (const float*)d_in[1];
    const float* ba = (const float*)d_in[2];
    const float* wp = (const float*)d_in[3];
    const float* bp = (const float*)d_in[4];
    float* out = (float*)d_out;

    char* ws = (char*)d_ws;
    _Float16* y   = (_Float16*)(ws);                    // [0,16M)   attn out
    _Float16* qn  = (_Float16*)(ws + 16777216);         // [16M,32M)
    _Float16* kP  = (_Float16*)(ws + 33554432);         // [32M,48M)
    _Float16* vP  = (_Float16*)(ws + 50331648);         // [48M,64M)
    _Float16* waT = (_Float16*)(ws + 67108864);         // [64M,70M)
    _Float16* wpT = (_Float16*)(ws + 73400320);         // [70M,72M)
    _Float16* xh  = (_Float16*)(ws + 75497472);         // [72M,88M) dead after gemm_qkv

    conv_x<<<4096, 256, 0, stream>>>((const float4*)x, xh, 8388608 / 4);
    tconv2<<<dim3(64, 16), 256, 0, stream>>>(wa, waT, wp, wpT);
    gemm_qkv<<<dim3(12, 32), 512, 0, stream>>>(xh, waT, ba, qn, kP, vP);
    attn<<<dim3(32, 128), 512, 0, stream>>>(qn, kP, vP, y);
    gemm_proj<<<dim3(8, 32), 512, 0, stream>>>(y, wpT, bp, out, 1024);
}

// Round 6
// 244.296 us; speedup vs baseline: 1.2216x; 1.0573x over previous
//
#include <hip/hip_runtime.h>

// TreeAttentionV2: B=8, T=1024, C=1024 (L=4,R=256), H=16, hd=64.
// Pipeline (all fp16 MFMA, fp32 accumulate):
//   1. prep:      x fp32 -> xh fp16 (grid-stride) AND both weight transposes (one launch)
//   2. gemm_qkv:  qn/kP/vP = xh @ waT^T + b_attn. 256x256x64 8-phase; fused-pack epilogue;
//                 XCD-chunked grid swizzle.
//   3. attn v9:   32-row q-tile, 8 waves, k-sliced, XCD-swizzled. Phase1: all 16 K-frags
//                 preloaded to regs (full unroll, L2 latency hidden), exp2-direct, split
//                 lpart chains. Phase2: 16 V-frags preloaded. Phase3: red slice w overlays
//                 wave w's OWN E columns (wave-private) -> phase2/3 barrier removed.
//   4. gemm_proj: out = y @ wpT^T + b_proj (256x128 8-phase, 1 exact round, XCD swizzle)
//
// Workspace (88 MiB):
//   [0,16M)   y    (attn output; region free until attn)
//   [16M,32M) qn ; [32M,48M) kP ; [48M,64M) vP
//   [64M,70M) waT ; [70M,72M) wpT ; [72M,88M) xh (dead after gemm_qkv)

typedef _Float16 half8 __attribute__((ext_vector_type(8)));
typedef _Float16 half4_t __attribute__((ext_vector_type(4)));
typedef float floatx4 __attribute__((ext_vector_type(4)));

__device__ __forceinline__ void gl2lds16(const void* gsrc, void* lds) {
    __builtin_amdgcn_global_load_lds(
        (const __attribute__((address_space(1))) unsigned int*)gsrc,
        (__attribute__((address_space(3))) unsigned int*)lds,
        16, 0, 0);
}

// ---------------- prep: conv_x (blocks 0..4095) + weight transposes (4096..5119) ----------
__global__ __launch_bounds__(256) void prep(const float4* __restrict__ x4,
                                            _Float16* __restrict__ xh,
                                            const float* __restrict__ wa,
                                            _Float16* __restrict__ waT,
                                            const float* __restrict__ wp,
                                            _Float16* __restrict__ wpT) {
    __shared__ _Float16 t[64 * 65];
    int bid = blockIdx.x;
    if (bid < 4096) {
        int idx = bid * 256 + threadIdx.x;
#pragma unroll
        for (int i = idx; i < 2097152; i += 1048576) {
            float4 v = x4[i];
            half4_t h = { (_Float16)v.x, (_Float16)v.y, (_Float16)v.z, (_Float16)v.w };
            *(half4_t*)(xh + (size_t)i * 4) = h;
        }
    } else {
        int tt = bid - 4096;
        int by = tt & 15, bx = tt >> 4;
        const float* in = wa; _Float16* out = waT; int C = 3072;
        if (bx >= 48) { bx -= 48; in = wp; out = wpT; C = 1024; }
#pragma unroll
        for (int it = 0; it < 16; ++it) {
            int idx = it * 256 + threadIdx.x;
            int r = idx >> 6, c = idx & 63;
            t[c * 65 + r] = (_Float16)in[(size_t)(by * 64 + r) * C + bx * 64 + c];
        }
        __syncthreads();
#pragma unroll
        for (int it = 0; it < 16; ++it) {
            int idx = it * 256 + threadIdx.x;
            int rn = idx >> 6, ck = idx & 63;
            out[(size_t)(bx * 64 + rn) * 1024 + by * 64 + ck] = t[rn * 65 + ck];
        }
    }
}

// common pipeline helpers
#define GBAR __builtin_amdgcn_s_barrier()
#define WLGKM do { asm volatile("s_waitcnt lgkmcnt(0)" ::: "memory"); } while (0)
#define WVM2  do { asm volatile("s_waitcnt vmcnt(2)"   ::: "memory"); } while (0)
#define WVM4  do { asm volatile("s_waitcnt vmcnt(4)"   ::: "memory"); } while (0)
#define WVM0  do { asm volatile("s_waitcnt vmcnt(0)"   ::: "memory"); } while (0)

// ================= gemm_qkv: 256x256 8-phase + fused-pack epilogue + XCD swizzle ======
// BM=256, BN=256, BK=64, K=1024. 512 threads = 8 waves (2M x 4N), per-wave 128x64.
// LDS 128KB. XOR-swizzle via inverse-swizzled global source. WVM4 at P4/P8 only.
// kP chunk c holds K[t=(c>>7&63)*16+(c&15)][d=(c>>6&1)*32+((c>>4)&3)*8+j]  (c per bh<<13)
// vP chunk c holds V^T[d=((c&255)>>6)*16+(c&15)][k=(c>>8&31)*32+((c>>4)&3)*8+j] (per bh<<13)

#define WLDA(buf, rg)                                                                         \
    do {                                                                                      \
        _Pragma("unroll") for (int i = 0; i < 4; ++i) {                                       \
            int r_ = wm * 128 + ((rg) * 4 + i) * 16 + l15;                                    \
            _Pragma("unroll") for (int kk = 0; kk < 2; ++kk)                                  \
                a[i][kk] = *(const half8*)(sA + (buf) * 32768 + r_ * 128 +                    \
                                           ((((kk << 2) + quad) ^ (r_ & 7)) << 4));           \
        }                                                                                     \
    } while (0)

#define WLDB(buf, cg, bb)                                                                     \
    do {                                                                                      \
        _Pragma("unroll") for (int j = 0; j < 2; ++j) {                                       \
            int r_ = wn * 64 + ((cg) * 2 + j) * 16 + l15;                                     \
            _Pragma("unroll") for (int kk = 0; kk < 2; ++kk)                                  \
                bb[j][kk] = *(const half8*)(sB + (buf) * 32768 + r_ * 128 +                   \
                                            ((((kk << 2) + quad) ^ (r_ & 7)) << 4));          \
        }                                                                                     \
    } while (0)

#define WMMA(rg, cg, bb)                                                                      \
    do {                                                                                      \
        __builtin_amdgcn_s_setprio(1);                                                        \
        _Pragma("unroll") for (int kk = 0; kk < 2; ++kk)                                      \
            _Pragma("unroll") for (int i = 0; i < 4; ++i)                                     \
                _Pragma("unroll") for (int j = 0; j < 2; ++j)                                  \
                    acc[(rg) * 4 + i][(cg) * 2 + j] = __builtin_amdgcn_mfma_f32_16x16x32_f16( \
                        a[i][kk], bb[j][kk], acc[(rg) * 4 + i][(cg) * 2 + j], 0, 0, 0);       \
        __builtin_amdgcn_s_setprio(0);                                                        \
    } while (0)

__global__ __launch_bounds__(512, 2) void gemm_qkv(const _Float16* __restrict__ A,
                                                   const _Float16* __restrict__ BT,
                                                   const float* __restrict__ bias,
                                                   _Float16* __restrict__ qno,
                                                   _Float16* __restrict__ kPo,
                                                   _Float16* __restrict__ vPo) {
    __shared__ __attribute__((aligned(16))) char lds[131072];
    char* sA = lds;           // + buf*32768 + half*16384 + rnd*8192
    char* sB = lds + 65536;
    int tid = threadIdx.x;
    int W = tid >> 6, lane = tid & 63, quad = lane >> 4, l15 = lane & 15;
    int wm = W >> 2, wn = W & 3;
    // XCD-chunked swizzle (bijective: 384 % 8 == 0): each XCD gets 48 contiguous tiles
    // (= 4 full m-rows sharing 4 A-panels + the whole 6MB waT -> fits its L2).
    int flat = blockIdx.y * 12 + blockIdx.x;
    int swz = (flat & 7) * 48 + (flat >> 3);
    int m0 = (swz / 12) * 256, n0 = (swz % 12) * 256;

    auto stA = [&](int buf, int half, int k0) {
#pragma unroll
        for (int rnd = 0; rnd < 2; ++rnd) {
            int c = rnd * 512 + tid;
            int row = c >> 3;
            int q = (c & 7) ^ (row & 7);
            const _Float16* src = A + (size_t)(m0 + half * 128 + row) * 1024 + k0 + q * 8;
            int off = __builtin_amdgcn_readfirstlane(buf * 32768 + half * 16384 +
                                                     rnd * 8192 + (W << 10));
            gl2lds16(src, sA + off);
        }
    };
    auto stB = [&](int buf, int half, int k0) {
#pragma unroll
        for (int rnd = 0; rnd < 2; ++rnd) {
            int c = rnd * 512 + tid;
            int row = c >> 3;
            int q = (c & 7) ^ (row & 7);
            const _Float16* src = BT + (size_t)(n0 + half * 128 + row) * 1024 + k0 + q * 8;
            int off = __builtin_amdgcn_readfirstlane(buf * 32768 + half * 16384 +
                                                     rnd * 8192 + (W << 10));
            gl2lds16(src, sB + off);
        }
    };

    half8 a[4][2], b0[2][2], b1[2][2];
    floatx4 acc[8][4] = {};

    stA(0, 0, 0); stA(0, 1, 0);
    stB(0, 0, 0); stB(0, 1, 0);
    stB(1, 0, 64); stB(1, 1, 64);
    WVM4;
    GBAR;

#pragma unroll 1
    for (int t = 0; t < 16; t += 2) {
        int k1 = (t + 1) << 6;
        int k2 = ((t + 2) & 15) << 6;   // wraps last iter: garbage into dead bufs
        int k3 = ((t + 3) & 15) << 6;
        WLDA(0, 0); WLDB(0, 0, b0); stA(1, 0, k1);
        GBAR; WLGKM; WMMA(0, 0, b0); GBAR;                 // P1
        WLDB(0, 1, b1); stA(1, 1, k1);
        GBAR; WLGKM; WMMA(0, 1, b1); GBAR;                 // P2
        WLDA(0, 1); stB(0, 0, k2);
        GBAR; WLGKM; WMMA(1, 1, b1); GBAR;                 // P3
        stB(0, 1, k2); WVM4;
        GBAR; WLGKM; WMMA(1, 0, b0); GBAR;                 // P4
        WLDA(1, 0); WLDB(1, 0, b0); stA(0, 0, k2);
        GBAR; WLGKM; WMMA(0, 0, b0); GBAR;                 // P5
        WLDB(1, 1, b1); stA(0, 1, k2);
        GBAR; WLGKM; WMMA(0, 1, b1); GBAR;                 // P6
        WLDA(1, 1); stB(1, 0, k3);
        GBAR; WLGKM; WMMA(1, 1, b1); GBAR;                 // P7
        stB(1, 1, k3); WVM4;
        GBAR; WLGKM; WMMA(1, 0, b0); GBAR;                 // P8
    }

    // ---- fused-pack epilogue: two column-half passes (128 cols each) ----
    WVM0;          // trailing prefetch DMA must land before LDS reuse
    GBAR;
    int sec = n0 >> 10;          // 0=Q 1=K 2=V (256-tiles never straddle 1024)
    int b = m0 >> 10;            // batch (BM=256 stays within one b)
    int tb = m0 & 1023;          // token base
#pragma unroll 1
    for (int p = 0; p < 2; ++p) {
        if (p) __syncthreads();          // pass-0 reads done before restage
        if (sec == 2) {
            // V: stage transposed [lc=128][m=256], row stride 528B
            if ((wn >> 1) == p) {
#pragma unroll
                for (int cf = 0; cf < 4; ++cf) {
                    int lc = (wn & 1) * 64 + cf * 16 + l15;
                    float bv = bias[n0 + wn * 64 + cf * 16 + l15];
#pragma unroll
                    for (int rf = 0; rf < 8; ++rf) {
                        int m = wm * 128 + rf * 16 + quad * 4;   // m&7 in {0,4}: 8B aligned
                        half4_t h4;
#pragma unroll
                        for (int r = 0; r < 4; ++r) h4[r] = (_Float16)(acc[rf][cf][r] + bv);
                        *(half4_t*)(lds + lc * 528 + m * 2) = h4;
                    }
                }
            }
            __syncthreads();
            int l15v = tid & 15;
            int moct = W * 4 + ((tid >> 4) & 3);     // m-octet 0..31
            int t = tb + moct * 8;
            int kbv = (t >> 5) & 31, quad_v = (t >> 3) & 3;
            int nbV = (n0 & 1023) + p * 128;
#pragma unroll
            for (int i = 0; i < 8; ++i) {
                int hh = i >> 2, cf = i & 3;
                int n = hh * 64 + cf * 16 + l15v;
                half8 v = *(const half8*)(lds + n * 528 + (moct << 4));
                int gcol = nbV + n;
                int h = gcol >> 6, d = gcol & 63;
                size_t chunk = (size_t)((b * 16 + h) * 32 + kbv) * 256 +
                               (d >> 4) * 64 + quad_v * 16 + (d & 15);
                *(half8*)(vPo + chunk * 8) = v;
            }
        } else {
            // Q/K: stage [m=256][lc=128], row stride 272B
            if ((wn >> 1) == p) {
#pragma unroll
                for (int cf = 0; cf < 4; ++cf) {
                    int lc = (wn & 1) * 64 + cf * 16 + l15;
                    float bv = bias[n0 + wn * 64 + cf * 16 + l15];
#pragma unroll
                    for (int rf = 0; rf < 8; ++rf) {
                        int m = wm * 128 + rf * 16 + quad * 4;
#pragma unroll
                        for (int r = 0; r < 4; ++r)
                            *(_Float16*)(lds + (m + r) * 272 + lc * 2) =
                                (_Float16)(acc[rf][cf][r] + bv);
                    }
                }
            }
            __syncthreads();
            int nb = (n0 & 1023) + p * 128;
            if (sec == 0) {
                int noct = tid & 15;
#pragma unroll
                for (int i = 0; i < 8; ++i) {
                    int m = i * 32 + (tid >> 4);
                    half8 v = *(const half8*)(lds + m * 272 + (noct << 4));
                    *(half8*)(qno + (size_t)(b * 1024 + tb + m) * 1024 + nb + noct * 8) = v;
                }
            } else {
                int l15k = tid & 15, noct = (tid >> 4) & 15;
#pragma unroll
                for (int i = 0; i < 8; ++i) {
                    int mb = i * 2 + (tid >> 8);
                    int m = mb * 16 + l15k;
                    half8 v = *(const half8*)(lds + m * 272 + (noct << 4));
                    int gcol = nb + noct * 8;
                    int h = gcol >> 6, d0 = gcol & 63;
                    int t = tb + m;
                    size_t chunk = (size_t)((b * 16 + h) * 64 + (t >> 4)) * 128 +
                                   (d0 >> 5) * 64 + ((d0 >> 3) & 3) * 16 + l15k;
                    *(half8*)(kPo + chunk * 8) = v;
                }
            }
        }
    }
}

// ================= gemm_proj: 256x128 8-phase, f32 out, XCD swizzle =================
#define LDA(buf, rg)                                                                          \
    do {                                                                                      \
        _Pragma("unroll") for (int i = 0; i < 2; ++i) {                                       \
            int r_ = wm * 64 + ((rg) * 2 + i) * 16 + l15;                                     \
            _Pragma("unroll") for (int kk = 0; kk < 2; ++kk)                                  \
                a[i][kk] = *(const half8*)(sA + (buf) * 32768 + r_ * 128 +                    \
                                           ((((kk << 2) + quad) ^ (r_ & 7)) << 4));           \
        }                                                                                     \
    } while (0)

#define LDB(buf, cg, bb)                                                                      \
    do {                                                                                      \
        _Pragma("unroll") for (int j = 0; j < 2; ++j) {                                       \
            int r_ = wn * 64 + ((cg) * 2 + j) * 16 + l15;                                     \
            _Pragma("unroll") for (int kk = 0; kk < 2; ++kk)                                  \
                bb[j][kk] = *(const half8*)(sB + (buf) * 16384 + r_ * 128 +                   \
                                            ((((kk << 2) + quad) ^ (r_ & 7)) << 4));          \
        }                                                                                     \
    } while (0)

#define MMA(rg, cg, bb)                                                                       \
    do {                                                                                      \
        __builtin_amdgcn_s_setprio(1);                                                        \
        _Pragma("unroll") for (int kk = 0; kk < 2; ++kk)                                      \
            _Pragma("unroll") for (int i = 0; i < 2; ++i)                                     \
                _Pragma("unroll") for (int j = 0; j < 2; ++j)                                  \
                    acc[(rg) * 2 + i][(cg) * 2 + j] = __builtin_amdgcn_mfma_f32_16x16x32_f16( \
                        a[i][kk], bb[j][kk], acc[(rg) * 2 + i][(cg) * 2 + j], 0, 0, 0);       \
        __builtin_amdgcn_s_setprio(0);                                                        \
    } while (0)

__global__ __launch_bounds__(512, 2) void gemm_proj(const _Float16* __restrict__ A,
                                                    const _Float16* __restrict__ BT,
                                                    const float* __restrict__ bias,
                                                    float* __restrict__ o0, int N) {
    __shared__ __attribute__((aligned(16))) char lds[98304];
    char* sA = lds;
    char* sB = lds + 65536;
    int tid = threadIdx.x;
    int W = tid >> 6, lane = tid & 63, quad = lane >> 4, l15 = lane & 15;
    int wm = W >> 1, wn = W & 1;
    // XCD-chunked swizzle (256 % 8 == 0): 32 contiguous tiles per XCD.
    int flat = blockIdx.y * 8 + blockIdx.x;
    int swz = (flat & 7) * 32 + (flat >> 3);
    int m0 = (swz >> 3) * 256, n0 = (swz & 7) * 128;

    auto stA = [&](int buf, int half, int k0) {
#pragma unroll
        for (int rnd = 0; rnd < 2; ++rnd) {
            int c = rnd * 512 + tid;
            int row = c >> 3;
            int q = (c & 7) ^ (row & 7);
            const _Float16* src = A + (size_t)(m0 + half * 128 + row) * 1024 + k0 + q * 8;
            int off = __builtin_amdgcn_readfirstlane(buf * 32768 + half * 16384 +
                                                     rnd * 8192 + (W << 10));
            gl2lds16(src, sA + off);
        }
    };
    auto stB = [&](int buf, int half, int k0) {
        int row = tid >> 3;
        int q = (tid & 7) ^ (row & 7);
        const _Float16* src = BT + (size_t)(n0 + half * 64 + row) * 1024 + k0 + q * 8;
        int off = __builtin_amdgcn_readfirstlane(buf * 16384 + half * 8192 + (W << 10));
        gl2lds16(src, sB + off);
    };

    half8 a[2][2], b0[2][2], b1[2][2];
    floatx4 acc[4][4] = {};

    stA(0, 0, 0); stA(0, 1, 0);
    stB(0, 0, 0); stB(0, 1, 0);
    stB(1, 0, 64); stB(1, 1, 64);
    WVM2;
    GBAR;

#pragma unroll 1
    for (int t = 0; t < 16; t += 2) {
        int k1 = (t + 1) << 6;
        int k2 = ((t + 2) & 15) << 6;
        int k3 = ((t + 3) & 15) << 6;
        LDA(0, 0); LDB(0, 0, b0); stA(1, 0, k1);
        GBAR; WLGKM; MMA(0, 0, b0); GBAR;
        LDB(0, 1, b1); stA(1, 1, k1);
        GBAR; WLGKM; MMA(0, 1, b1); GBAR;
        LDA(0, 1); stB(0, 0, k2);
        GBAR; WLGKM; MMA(1, 1, b1); GBAR;
        stB(0, 1, k2); WVM2;
        GBAR; WLGKM; MMA(1, 0, b0); GBAR;
        LDA(1, 0); LDB(1, 0, b0); stA(0, 0, k2);
        GBAR; WLGKM; MMA(0, 0, b0); GBAR;
        LDB(1, 1, b1); stA(0, 1, k2);
        GBAR; WLGKM; MMA(0, 1, b1); GBAR;
        LDA(1, 1); stB(1, 0, k3);
        GBAR; WLGKM; MMA(1, 1, b1); GBAR;
        stB(1, 1, k3); WVM2;
        GBAR; WLGKM; MMA(1, 0, b0); GBAR;
    }

#pragma unroll
    for (int cf = 0; cf < 4; ++cf) {
        int gn = n0 + wn * 64 + cf * 16 + l15;
        float bv = bias[gn];
#pragma unroll
        for (int rf = 0; rf < 4; ++rf) {
            int gmBase = m0 + wm * 64 + rf * 16 + quad * 4;
#pragma unroll
            for (int r = 0; r < 4; ++r)
                o0[(size_t)(gmBase + r) * N + gn] = acc[rf][cf][r] + bv;
        }
    }
}

// ------------------------------- attention v9 -------------------------------
// grid 4096 blocks (32 q-tiles x 128 bh), 512 threads = 8 waves; wave w owns k-slice
// [w*128, w*128+128). XCD swizzle (r3/r4-proven).
// LDS: E = 32 q-rows x 1024 k fp16 (64KB, xor-swizzled 16B granules); lsum 8x32 f32.
// Phase1: ALL 16 K-fragments preloaded to regs (hides L2 latency), then MFMA+exp2;
//         lpart split into 2 alternating chains per nf.
// Phase2: 16 V-fragments preloaded; normalize+threshold fused in A-frags.
// Phase3: red slice w overlays wave w's OWN E byte-columns [W*256, W*256+256) --
//         phase2 reads and phase3 writes are wave-private there, so NO barrier between
//         them; single barrier before the cross-wave final sum. (2 barriers total.)
__device__ __forceinline__ int esw(int row, int colByte) {
    return row * 2048 + (colByte ^ ((row & 7) << 4));
}

__global__ __launch_bounds__(512, 4) void attn(const _Float16* __restrict__ qn,
                                               const _Float16* __restrict__ kP,
                                               const _Float16* __restrict__ vP,
                                               _Float16* __restrict__ y) {
    __shared__ __attribute__((aligned(16))) _Float16 E[32 * 1024];
    __shared__ float lsum[8][32];
    char* Eb = (char*)E;
    int tid = threadIdx.x;
    int W = tid >> 6, lane = tid & 63, quad = lane >> 4, l15 = lane & 15;
    int flat = blockIdx.y * 32 + blockIdx.x;
    int swz = (flat & 7) * 512 + (flat >> 3);     // bijective, 4096 % 8 == 0
    int qt = swz & 31, bh = swz >> 5;
    int b = bh >> 4, h = bh & 15;
    int q0 = qt * 32;

    // --- Q as B-fragments (B[k=quad*8+j][n=l15]): n = q-row, k = d ---
    half8 bq[2][2];
#pragma unroll
    for (int nf = 0; nf < 2; ++nf)
#pragma unroll
        for (int ks = 0; ks < 2; ++ks)
            bq[nf][ks] = *(const half8*)(qn + (size_t)(b * 1024 + q0 + nf * 16 + l15) * 1024 +
                                         h * 64 + ks * 32 + quad * 8);

    // --- Phase 1: preload all 16 K-fragments (contiguous 1KB per wave per pair) ---
    half8 ak[8][2];
#pragma unroll
    for (int mt = 0; mt < 8; ++mt) {
        const _Float16* kp = kP + ((size_t)(bh * 64 + W * 8 + mt) * 128 + lane) * 8;
        ak[mt][0] = *(const half8*)(kp);
        ak[mt][1] = *(const half8*)(kp + 512);
    }
    // S^T = K.Q^T, e = exp2(s*c) -> E; rowsum partials in 2 alternating chains per nf
    float lp0[2] = {0.f, 0.f}, lp1[2] = {0.f, 0.f};
#pragma unroll
    for (int mt = 0; mt < 8; ++mt) {
#pragma unroll
        for (int nf = 0; nf < 2; ++nf) {
            floatx4 s = {};
            s = __builtin_amdgcn_mfma_f32_16x16x32_f16(ak[mt][0], bq[nf][0], s, 0, 0, 0);
            s = __builtin_amdgcn_mfma_f32_16x16x32_f16(ak[mt][1], bq[nf][1], s, 0, 0, 0);
            half4_t h4;
            float esum0 = 0.f, esum1 = 0.f;
#pragma unroll
            for (int r = 0; r < 4; ++r) {
                // exp(min(s/8,10)) == exp2(min(s*0.125*log2e, 14.4269504))
                float e = __builtin_amdgcn_exp2f(fminf(s[r] * 0.18033688f, 14.4269504f));
                if (r & 1) esum1 += e; else esum0 += e;
                h4[r] = (_Float16)e;
            }
            lp0[nf] += esum0;
            lp1[nf] += esum1;
            int q = nf * 16 + l15;
            int kbyte = (W * 128 + mt * 16 + quad * 4) * 2;
            *(half4_t*)(Eb + q * 2048 + (kbyte ^ ((q & 7) << 4))) = h4;
        }
    }
    // reduce over the 4 quads (lanes sharing l15)
#pragma unroll
    for (int nf = 0; nf < 2; ++nf) {
        float lp = lp0[nf] + lp1[nf];
        lp += __shfl_xor(lp, 16);
        lp += __shfl_xor(lp, 32);
        if (lane < 16) lsum[W][nf * 16 + l15] = lp;
    }
    __syncthreads();

    // --- Phase 2: PV over wave's k-slice; normalize+threshold fused in regs ---
    half8 bv[4][4];
#pragma unroll
    for (int kt = 0; kt < 4; ++kt) {
        const _Float16* vbase = vP + ((size_t)(bh * 32 + (W * 4 + kt)) * 256 + lane) * 8;
#pragma unroll
        for (int cf = 0; cf < 4; ++cf)
            bv[kt][cf] = *(const half8*)(vbase + cf * 512);   // contiguous 1KB / wave
    }
    half8 inv8[2], t8, z8;
#pragma unroll
    for (int j = 0; j < 8; ++j) { t8[j] = (_Float16)(-0.001f); z8[j] = (_Float16)0.f; }
#pragma unroll
    for (int rf = 0; rf < 2; ++rf) {
        float l = 0.f;
#pragma unroll
        for (int w = 0; w < 8; ++w) l += lsum[w][rf * 16 + l15];
        _Float16 invh = (_Float16)(1.0f / l);
#pragma unroll
        for (int j = 0; j < 8; ++j) inv8[rf][j] = invh;
    }

    floatx4 acc[2][4] = {};
#pragma unroll
    for (int kt = 0; kt < 4; ++kt) {
        int kk = W * 128 + kt * 32;
        half8 ap[2];
#pragma unroll
        for (int rf = 0; rf < 2; ++rf) {
            ap[rf] = *(const half8*)(Eb + esw(rf * 16 + l15, (kk + quad * 8) * 2));
            ap[rf] = ap[rf] * inv8[rf] + t8;                        // v_pk_fma_f16
            ap[rf] = __builtin_elementwise_max(ap[rf], z8);         // v_pk_max_f16
        }
#pragma unroll
        for (int rf = 0; rf < 2; ++rf)
#pragma unroll
            for (int cf = 0; cf < 4; ++cf)
                acc[rf][cf] = __builtin_amdgcn_mfma_f32_16x16x32_f16(ap[rf], bv[kt][cf], acc[rf][cf], 0, 0, 0);
    }

    // --- Phase 3: write partials into wave-OWN E columns (no barrier needed: wave w's
    //     phase-2 reads and these writes both touch only bytes row*2048 + W*256 + [0,256) )
#pragma unroll
    for (int rf = 0; rf < 2; ++rf)
#pragma unroll
        for (int cf = 0; cf < 4; ++cf)
#pragma unroll
            for (int r = 0; r < 4; ++r) {
                int row = rf * 16 + quad * 4 + r;
                *(float*)(Eb + row * 2048 + W * 256 + (cf * 16 + l15) * 4) = acc[rf][cf][r];
            }
    __syncthreads();
    {
        int e4 = tid * 4;                 // 512 thr x 4 = 2048 = 32 rows x 64 d
        int r = e4 >> 6, c = e4 & 63;
        floatx4 s = {};
#pragma unroll
        for (int w = 0; w < 8; ++w)
            s += *(const floatx4*)(Eb + r * 2048 + w * 256 + c * 4);
        half4_t hv = { (_Float16)s[0], (_Float16)s[1], (_Float16)s[2], (_Float16)s[3] };
        *(half4_t*)(y + (size_t)(b * 1024 + q0 + r) * 1024 + h * 64 + c) = hv;
    }
}

// ------------------------------- launcher -------------------------------
extern "C" void kernel_launch(void* const* d_in, const int* in_sizes, int n_in,
                              void* d_out, int out_size, void* d_ws, size_t ws_size,
                              hipStream_t stream) {
    const float* x  = (const float*)d_in[0];
    const float* wa = (const float*)d_in[1];
    const float* ba = (const float*)d_in[2];
    const float* wp = (const float*)d_in[3];
    const float* bp = (const float*)d_in[4];
    float* out = (float*)d_out;

    char* ws = (char*)d_ws;
    _Float16* y   = (_Float16*)(ws);                    // [0,16M)   attn out
    _Float16* qn  = (_Float16*)(ws + 16777216);         // [16M,32M)
    _Float16* kP  = (_Float16*)(ws + 33554432);         // [32M,48M)
    _Float16* vP  = (_Float16*)(ws + 50331648);         // [48M,64M)
    _Float16* waT = (_Float16*)(ws + 67108864);         // [64M,70M)
    _Float16* wpT = (_Float16*)(ws + 73400320);         // [70M,72M)
    _Float16* xh  = (_Float16*)(ws + 75497472);         // [72M,88M) dead after gemm_qkv

    prep<<<5120, 256, 0, stream>>>((const float4*)x, xh, wa, waT, wp, wpT);
    gemm_qkv<<<dim3(12, 32), 512, 0, stream>>>(xh, waT, ba, qn, kP, vP);
    attn<<<dim3(32, 128), 512, 0, stream>>>(qn, kP, vP, y);
    gemm_proj<<<dim3(8, 32), 512, 0, stream>>>(y, wpT, bp, out, 1024);
}